// Round 1
// baseline (251.551 us; speedup 1.0000x reference)
//
#include <hip/hip_runtime.h>
#include <hip/hip_bf16.h>
#include <math.h>

// Problem constants (from reference)
constexpr int N_ENT = 100000;
constexpr int NEDGE = 1600000;
constexpr int BATCH = 8192;
constexpr int NBLK_SCAN = (N_ENT + 255) / 256;   // 391

// Bucketed CSR placement
constexpr int NBUCK   = 256;
constexpr int KNODE   = 391;                      // 256*391 >= N_ENT
constexpr int TILE    = 4096;
constexpr int NTILE   = (NEDGE + TILE - 1) / TILE; // 391
constexpr int BUCKCAP = 8192;                     // fixed bucket region

constexpr int NBLK_G = (N_ENT + 63) / 64;         // 1563 (64-row MLP tiles)
constexpr int ZROWS  = NBLK_G * 64;               // 100032 <= padded zb rows

// Planar (dim-sliced) layouts: 2 planes of 32 cols each.
// [R14 theory] reduce1's 12.8MB gather set vs 4MB/XCD L2 -> 69% capacity
// misses (FETCH 156MB). Two 6.4MB planes gathered in two sequential passes
// raise the per-pass L2 hit rate to ~62% (predicted FETCH ~95-110MB).
constexpr int    NBLK_R1 = N_ENT * 64 / 256;             // 25000 blocks/pass
constexpr size_t EPLANE  = (size_t)(N_ENT + 1) * 32;     // ushorts per emb plane
constexpr size_t ZPLANE  = (size_t)ZROWS * 32;           // ushorts per zb plane

// MFMA fragment types (gfx950; 8 bf16 = 4 VGPRs, 4 f32 acc)
typedef __attribute__((ext_vector_type(8))) short bf16x8;
typedef __attribute__((ext_vector_type(4))) float f32x4;

// bf16 helpers (RNE pack, exact unpack)
__device__ inline unsigned short f2b(float x) {
    unsigned int u = __float_as_uint(x);
    unsigned int r = (u + 0x7fffu + ((u >> 16) & 1u)) >> 16;
    return (unsigned short)r;
}
__device__ inline float b2f(unsigned short h) {
    return __uint_as_float(((unsigned int)h) << 16);
}
__device__ inline float blo(unsigned int p) { return __uint_as_float(p << 16); }
__device__ inline float bhi(unsigned int p) { return __uint_as_float(p & 0xffff0000u); }

// ---------------------------------------------------------------------------
// Workspace layout (4-byte units):
//  degi      : [0, 100000)
//  dinv      : [100000, 200000)
//  row_start : [200000, 300001)
//  gcursor   : [300004, 300260)
//  partials  : [300264, 300655)
//  w1p       : [300656, 304752)    uint4[1024] packed W1 B-frags (bf16)
//  w2p       : [304752, 308848)    uint4[1024] packed W2 B-frags (bf16)
//  srcs      : [308848, 1908848)
//  emb_b     : [1908848, 3508864)  ushort[2 planes * (N+1)*32]
//  zb        : [3508864, 6711936)  ushort[2 planes * 100032*32]
//  h2b       : [6711936, 8311968)  ushort[(N+1)*64]  (interleaved 128B rows)
//  temp      : [8311968, 10409120) uint[256*8192]
// Total ~41.6 MB.

// K1: prep — dinv + premultiplied bf16 entity rows, written as two
// 32-col planes (+ zero row at N_ENT in each plane)
__global__ __launch_bounds__(256) void prep_k(const float* __restrict__ emb,
                                              const int* __restrict__ degi,
                                              float* __restrict__ dinv,
                                              unsigned short* __restrict__ emb_b) {
    int gt   = blockIdx.x * 256 + threadIdx.x;
    int n    = gt >> 6;
    int lane = threadIdx.x & 63;
    if (n > N_ENT) return;
    int plane = lane >> 5;
    int cp    = lane & 31;
    if (n == N_ENT) { emb_b[(size_t)plane * EPLANE + (size_t)n * 32 + cp] = 0; return; }
    float v = emb[(size_t)n * 64 + lane];
    float s = v * v;
#pragma unroll
    for (int o = 32; o > 0; o >>= 1) s += __shfl_xor(s, o, 64);
    float nrm = sqrtf(s);
    float sc  = nrm > 1.0f ? 1.0f / nrm : 1.0f;
    float dv  = 1.0f / sqrtf((float)(degi[n] + 1));
    if (lane == 0) dinv[n] = dv;
    emb_b[(size_t)plane * EPLANE + (size_t)n * 32 + cp] = f2b(sc * dv * v);
}

// K0a: gcursor init to fixed bucket bases
__global__ __launch_bounds__(256) void ginit_k(int* __restrict__ gcursor) {
    gcursor[threadIdx.x] = threadIdx.x * BUCKCAP;
}

// K0p: pack W1/W2 into MFMA B-operand lane order (bf16).
// B-frag for mfma_f32_16x16x32_bf16: lane holds B[k = quad*8+j][n = lane&15].
// w1p entry e=(ct*2+s)*64+lane packs W1[s*32+quad*8+j][ct*16+li], j=0..7.
// w2p entry e=(ct*4+s)*64+lane packs W2[s*32+quad*8+j][ct*16+li].
__global__ __launch_bounds__(256) void packw_k(const float* __restrict__ W1g,
                                               const float* __restrict__ W2g,
                                               uint4* __restrict__ w1p,
                                               uint4* __restrict__ w2p) {
    int t = blockIdx.x * 256 + threadIdx.x;   // grid 8 -> 2048 threads
    int e    = t & 1023;
    int lane = e & 63, cs = e >> 6;
    int li   = lane & 15, quad = lane >> 4;
    unsigned short v[8];
    if (t < 1024) {
        int ct = cs >> 1, s = cs & 1;
        int kb = s * 32 + quad * 8;
        int n  = ct * 16 + li;
#pragma unroll
        for (int j = 0; j < 8; ++j) v[j] = f2b(W1g[(kb + j) * 128 + n]);
        uint4 p;
        p.x = (unsigned)v[0] | ((unsigned)v[1] << 16);
        p.y = (unsigned)v[2] | ((unsigned)v[3] << 16);
        p.z = (unsigned)v[4] | ((unsigned)v[5] << 16);
        p.w = (unsigned)v[6] | ((unsigned)v[7] << 16);
        w1p[e] = p;
    } else {
        int ct = cs >> 2, s = cs & 3;
        int kb = s * 32 + quad * 8;
        int n  = ct * 16 + li;
#pragma unroll
        for (int j = 0; j < 8; ++j) v[j] = f2b(W2g[(kb + j) * 64 + n]);
        uint4 p;
        p.x = (unsigned)v[0] | ((unsigned)v[1] << 16);
        p.y = (unsigned)v[2] | ((unsigned)v[3] << 16);
        p.z = (unsigned)v[4] | ((unsigned)v[5] << 16);
        p.w = (unsigned)v[6] | ((unsigned)v[7] << 16);
        w2p[e] = p;
    }
}

// K0b: bucket binning into fixed-capacity regions
__global__ __launch_bounds__(256) void bin_k(const int* __restrict__ edges,
                                             int* __restrict__ gcursor,
                                             unsigned int* __restrict__ temp) {
    __shared__ int cnt[NBUCK];
    __shared__ int gb[NBUCK];
    __shared__ int off[NBUCK];
    int tid  = threadIdx.x;
    int base = blockIdx.x * TILE;
    int sv[16], dv[16], bv[16];
    cnt[tid] = 0;
    __syncthreads();
#pragma unroll
    for (int i = 0; i < 16; ++i) {
        int e = base + i * 256 + tid;
        if (e < NEDGE) {
            sv[i] = edges[e];
            dv[i] = edges[NEDGE + e];
            bv[i] = dv[i] / KNODE;
            atomicAdd(&cnt[bv[i]], 1);
        } else {
            bv[i] = -1;
        }
    }
    __syncthreads();
    if (cnt[tid] > 0) gb[tid] = atomicAdd(&gcursor[tid], cnt[tid]);
    off[tid] = 0;
    __syncthreads();
#pragma unroll
    for (int i = 0; i < 16; ++i) {
        int b = bv[i];
        if (b >= 0) {
            int p  = atomicAdd(&off[b], 1);
            int dl = dv[i] - b * KNODE;
            temp[gb[b] + p] = ((unsigned int)sv[i] << 9) | (unsigned int)dl;
        }
    }
}

// K0c: per-bucket degree histogram from binned temp
__global__ __launch_bounds__(256) void count_k(const unsigned int* __restrict__ temp,
                                               const int* __restrict__ gcursor,
                                               int* __restrict__ degi) {
    __shared__ int cnt[KNODE];
    int b     = blockIdx.x;
    int node0 = b * KNODE;
    int nn    = N_ENT - node0; if (nn > KNODE) nn = KNODE;
    for (int i = threadIdx.x; i < KNODE; i += 256) cnt[i] = 0;
    __syncthreads();
    int tbeg = b * BUCKCAP;
    int tend = gcursor[b];
    for (int idx = tbeg + threadIdx.x; idx < tend; idx += 256)
        atomicAdd(&cnt[temp[idx] & 511u], 1);
    __syncthreads();
    for (int i = threadIdx.x; i < nn; i += 256) degi[node0 + i] = cnt[i];
}

// K3a/b/c: hierarchical exclusive scan of degi -> row_start
__global__ __launch_bounds__(256) void scan_partials(const int* __restrict__ degi,
                                                     int* __restrict__ partials) {
    __shared__ int ws[4];
    int i = blockIdx.x * 256 + threadIdx.x;
    int v = (i < N_ENT) ? degi[i] : 0;
#pragma unroll
    for (int o = 32; o > 0; o >>= 1) v += __shfl_xor(v, o, 64);
    if ((threadIdx.x & 63) == 0) ws[threadIdx.x >> 6] = v;
    __syncthreads();
    if (threadIdx.x == 0) partials[blockIdx.x] = ws[0] + ws[1] + ws[2] + ws[3];
}

__global__ __launch_bounds__(512) void scan_offsets(int* __restrict__ partials,
                                                    int* __restrict__ row_start) {
    __shared__ int ts[512];
    int t = threadIdx.x;
    int v = (t < NBLK_SCAN) ? partials[t] : 0;
    ts[t] = v;
    __syncthreads();
    for (int off = 1; off < 512; off <<= 1) {
        int x = (t >= off) ? ts[t - off] : 0;
        __syncthreads();
        ts[t] += x;
        __syncthreads();
    }
    if (t < NBLK_SCAN) partials[t] = ts[t] - v;
    if (t == 0) row_start[N_ENT] = NEDGE;
}

__global__ __launch_bounds__(256) void scan_apply(const int* __restrict__ degi,
                                                  const int* __restrict__ partials,
                                                  int* __restrict__ row_start) {
    __shared__ int ts[256];
    int t = threadIdx.x;
    int i = blockIdx.x * 256 + t;
    int v = (i < N_ENT) ? degi[i] : 0;
    ts[t] = v;
    __syncthreads();
    for (int off = 1; off < 256; off <<= 1) {
        int x = (t >= off) ? ts[t - off] : 0;
        __syncthreads();
        ts[t] += x;
        __syncthreads();
    }
    if (i < N_ENT) row_start[i] = ts[t] - v + partials[blockIdx.x];
}

// K4b: within-bucket placement
__global__ __launch_bounds__(256) void unbin_k(const unsigned int* __restrict__ temp,
                                               const int* __restrict__ gcursor,
                                               const int* __restrict__ row_start,
                                               int* __restrict__ srcs) {
    __shared__ int cur[KNODE];
    int b     = blockIdx.x;
    int node0 = b * KNODE;
    int nn    = N_ENT - node0; if (nn > KNODE) nn = KNODE;
    for (int i = threadIdx.x; i < nn; i += 256) cur[i] = row_start[node0 + i];
    __syncthreads();
    int tbeg = b * BUCKCAP;
    int tend = gcursor[b];
    for (int idx = tbeg + threadIdx.x; idx < tend; idx += 256) {
        unsigned int v = temp[idx];
        int dl = (int)(v & 511u);
        int s  = (int)(v >> 9);
        int pos = atomicAdd(&cur[dl], 1);
        srcs[pos] = s;
    }
}

// K5: layer-1 aggregate, dim-sliced into two passes over 32-col planes.
// pass = blockIdx.x / NBLK_R1 selects the plane; in-order dispatch keeps the
// passes mostly time-separated so each XCD's 4MB L2 sees a 6.4MB working set
// (predicted hit ~62%) instead of the full 12.8MB (hit ~31%, FETCH 156MB).
// 16 lanes per row, uint (2 bf16) per lane = 64B/row gather granule.
__global__ __launch_bounds__(256) void reduce1_k(const int* __restrict__ row_start,
                                                 const int* __restrict__ srcs,
                                                 const unsigned short* __restrict__ emb_b,
                                                 const float* __restrict__ dinv,
                                                 unsigned short* __restrict__ zb) {
    int pass = (blockIdx.x >= NBLK_R1) ? 1 : 0;
    int gt   = (blockIdx.x - pass * NBLK_R1) * 256 + threadIdx.x;
    int dst  = gt >> 6;
    int lane = threadIdx.x & 63;
    int sub  = lane >> 4;
    int li   = lane & 15;
    const unsigned short* eb = emb_b + (size_t)pass * EPLANE;
    int beg = row_start[dst];
    int end = row_start[dst + 1];
    float accx = 0.f, accy = 0.f;
    for (int base = beg; base < end; base += 64) {
        int cnt = end - base; if (cnt > 64) cnt = 64;
        int s_v = (base + lane < end) ? srcs[base + lane] : N_ENT;
        for (int jj = 0; jj < cnt; jj += 16) {
            int s0 = __shfl(s_v, jj + sub,      64);
            int s1 = __shfl(s_v, jj + 4 + sub,  64);
            int s2 = __shfl(s_v, jj + 8 + sub,  64);
            int s3 = __shfl(s_v, jj + 12 + sub, 64);
            unsigned int p0 = *(const unsigned int*)(eb + (size_t)s0 * 32 + li * 2);
            unsigned int p1 = *(const unsigned int*)(eb + (size_t)s1 * 32 + li * 2);
            unsigned int p2 = *(const unsigned int*)(eb + (size_t)s2 * 32 + li * 2);
            unsigned int p3 = *(const unsigned int*)(eb + (size_t)s3 * 32 + li * 2);
            accx += blo(p0) + blo(p1) + blo(p2) + blo(p3);
            accy += bhi(p0) + bhi(p1) + bhi(p2) + bhi(p3);
        }
    }
    accx += __shfl_xor(accx, 16, 64); accy += __shfl_xor(accy, 16, 64);
    accx += __shfl_xor(accx, 32, 64); accy += __shfl_xor(accy, 32, 64);
    if (lane < 16) {
        unsigned int po = *(const unsigned int*)(eb + (size_t)dst * 32 + li * 2);
        float dv = dinv[dst];
        unsigned int h0 = f2b(dv * (accx + blo(po)));
        unsigned int h1 = f2b(dv * (accy + bhi(po)));
        *(unsigned int*)(zb + (size_t)pass * ZPLANE + (size_t)dst * 32 + li * 2) =
            h0 | (h1 << 16);
    }
}

// K6: fused MFMA MLP: h2b = bf16(dinv * (relu(zb@W1 + b1) @ W2)).
// One wave per 16-row strip, 4 strips per block. MFMA 16x16x32_bf16:
//   A-frag: lane holds A[m=lane&15][k=quad*8+j]     [m120-verified layout]
//   C/D   : lane holds D[row=quad*4+r][col=lane&15] [m89/m91]
// zb is planar: a0 frag (k=0..31) from plane 0, a1 frag (k=32..63) from
// plane 1 — the A-frag k-split coincides exactly with the plane split.
// y1 (relu, bf16) round-trips through per-wave LDS between phases; h2b
// written via LDS transpose for coalesced uint4 stores (interleaved rows,
// consumed by reduce2f gathers).
__global__ __launch_bounds__(256) void mlp_k(const unsigned short* __restrict__ zb,
                                             const uint4* __restrict__ w1p,
                                             const float* __restrict__ b1,
                                             const uint4* __restrict__ w2p,
                                             const float* __restrict__ dinv,
                                             unsigned short* __restrict__ h2b) {
    __shared__ unsigned short y1s[4][16 * 136];   // per-wave y1 strip (pad 136)
    __shared__ unsigned short h2s[4][16 * 64];    // per-wave output strip
    int tid  = threadIdx.x;
    int w    = tid >> 6, lane = tid & 63;
    int li   = lane & 15, quad = lane >> 4;
    int r0   = blockIdx.x * 64 + w * 16;
    // phase-1 A frags (zb planes padded to ZROWS rows; garbage rows masked at store)
    uint4 a0u = *(const uint4*)(zb + (size_t)(r0 + li) * 32 + quad * 8);
    uint4 a1u = *(const uint4*)(zb + ZPLANE + (size_t)(r0 + li) * 32 + quad * 8);
    bf16x8 a0 = *(bf16x8*)&a0u;
    bf16x8 a1 = *(bf16x8*)&a1u;
    unsigned short* ys = y1s[w];
#pragma unroll
    for (int ct = 0; ct < 8; ++ct) {
        uint4 b0u = w1p[(ct * 2 + 0) * 64 + lane];
        uint4 b1u = w1p[(ct * 2 + 1) * 64 + lane];
        f32x4 acc = {0.f, 0.f, 0.f, 0.f};
        acc = __builtin_amdgcn_mfma_f32_16x16x32_bf16(a0, *(bf16x8*)&b0u, acc, 0, 0, 0);
        acc = __builtin_amdgcn_mfma_f32_16x16x32_bf16(a1, *(bf16x8*)&b1u, acc, 0, 0, 0);
        float bias = b1[ct * 16 + li];
#pragma unroll
        for (int r = 0; r < 4; ++r)
            ys[(quad * 4 + r) * 136 + ct * 16 + li] = f2b(fmaxf(acc[r] + bias, 0.f));
    }
    __syncthreads();
    // phase-2 A frags from LDS (A[m=li][k=s*32+quad*8+j])
    bf16x8 a2[4];
#pragma unroll
    for (int s = 0; s < 4; ++s) {
        uint4 au = *(const uint4*)(ys + li * 136 + s * 32 + quad * 8);
        a2[s] = *(bf16x8*)&au;
    }
    float dvr[4];
#pragma unroll
    for (int r = 0; r < 4; ++r) {
        int grow = r0 + quad * 4 + r;
        dvr[r] = (grow < N_ENT) ? dinv[grow] : 0.f;
    }
    unsigned short* hs = h2s[w];
#pragma unroll
    for (int ct = 0; ct < 4; ++ct) {
        f32x4 acc = {0.f, 0.f, 0.f, 0.f};
#pragma unroll
        for (int s = 0; s < 4; ++s) {
            uint4 bu = w2p[(ct * 4 + s) * 64 + lane];
            acc = __builtin_amdgcn_mfma_f32_16x16x32_bf16(a2[s], *(bf16x8*)&bu, acc, 0, 0, 0);
        }
#pragma unroll
        for (int r = 0; r < 4; ++r)
            hs[(quad * 4 + r) * 64 + ct * 16 + li] = f2b(acc[r] * dvr[r]);
    }
    __syncthreads();
    // coalesced store of the strip (2 uint4 per lane); zero row at N_ENT
#pragma unroll
    for (int q = 0; q < 2; ++q) {
        int t4   = lane * 2 + q;       // uint4 index within strip (0..127)
        int rl   = t4 >> 3;
        int c0   = (t4 & 7) * 8;
        int grow = r0 + rl;
        if (grow < N_ENT) {
            *(uint4*)(h2b + (size_t)grow * 64 + c0) = *(const uint4*)(hs + rl * 64 + c0);
        } else if (grow == N_ENT) {
            uint4 zz; zz.x = 0u; zz.y = 0u; zz.z = 0u; zz.w = 0u;
            *(uint4*)(h2b + (size_t)grow * 64 + c0) = zz;
        }
    }
}

// K8: fused layer-2 aggregate + final dot for the 8192 batch items.
__global__ __launch_bounds__(256) void reduce2f_k(const int* __restrict__ u,
                                                  const int* __restrict__ iidx,
                                                  const float* __restrict__ uemb,
                                                  const int* __restrict__ row_start,
                                                  const int* __restrict__ srcs,
                                                  const unsigned short* __restrict__ h2b,
                                                  const float* __restrict__ dinv,
                                                  const float* __restrict__ b2,
                                                  float* __restrict__ out) {
    int gt   = blockIdx.x * 256 + threadIdx.x;
    int b    = gt >> 6;
    int lane = threadIdx.x & 63;
    int sub  = lane >> 4;
    int li   = lane & 15;
    int dst = iidx[b];
    int beg = row_start[dst];
    int end = row_start[dst + 1];
    float4 acc = make_float4(0.f, 0.f, 0.f, 0.f);
    for (int base = beg; base < end; base += 64) {
        int cnt = end - base; if (cnt > 64) cnt = 64;
        int s_v = (base + lane < end) ? srcs[base + lane] : N_ENT;
        for (int jj = 0; jj < cnt; jj += 16) {
            int s0 = __shfl(s_v, jj + sub,      64);
            int s1 = __shfl(s_v, jj + 4 + sub,  64);
            int s2 = __shfl(s_v, jj + 8 + sub,  64);
            int s3 = __shfl(s_v, jj + 12 + sub, 64);
            uint2 p0 = *(const uint2*)(h2b + (size_t)s0 * 64 + li * 4);
            uint2 p1 = *(const uint2*)(h2b + (size_t)s1 * 64 + li * 4);
            uint2 p2 = *(const uint2*)(h2b + (size_t)s2 * 64 + li * 4);
            uint2 p3 = *(const uint2*)(h2b + (size_t)s3 * 64 + li * 4);
            acc.x += blo(p0.x) + blo(p1.x) + blo(p2.x) + blo(p3.x);
            acc.y += bhi(p0.x) + bhi(p1.x) + bhi(p2.x) + bhi(p3.x);
            acc.z += blo(p0.y) + blo(p1.y) + blo(p2.y) + blo(p3.y);
            acc.w += bhi(p0.y) + bhi(p1.y) + bhi(p2.y) + bhi(p3.y);
        }
    }
    acc.x += __shfl_xor(acc.x, 16, 64); acc.y += __shfl_xor(acc.y, 16, 64);
    acc.z += __shfl_xor(acc.z, 16, 64); acc.w += __shfl_xor(acc.w, 16, 64);
    acc.x += __shfl_xor(acc.x, 32, 64); acc.y += __shfl_xor(acc.y, 32, 64);
    acc.z += __shfl_xor(acc.z, 32, 64); acc.w += __shfl_xor(acc.w, 32, 64);
    float s1 = 0.f, s2 = 0.f;
    if (lane < 16) {
        uint2 po = *(const uint2*)(h2b + (size_t)dst * 64 + li * 4);
        float dv = dinv[dst];
        float4 bb = *(const float4*)(b2 + li * 4);
        float4 z2v;
        z2v.x = dv * (acc.x + blo(po.x)) + bb.x;
        z2v.y = dv * (acc.y + bhi(po.x)) + bb.y;
        z2v.z = dv * (acc.z + blo(po.y)) + bb.z;
        z2v.w = dv * (acc.w + bhi(po.y)) + bb.w;
        float4 ue = *(const float4*)(uemb + (size_t)u[b] * 64 + li * 4);
        s1 = ue.x * ue.x + ue.y * ue.y + ue.z * ue.z + ue.w * ue.w;
        s2 = ue.x * z2v.x + ue.y * z2v.y + ue.z * z2v.z + ue.w * z2v.w;
    }
#pragma unroll
    for (int o = 8; o > 0; o >>= 1) {
        s1 += __shfl_xor(s1, o, 64);
        s2 += __shfl_xor(s2, o, 64);
    }
    if (lane == 0) {
        float nrm = sqrtf(s1);
        float sc  = nrm > 1.0f ? 1.0f / nrm : 1.0f;
        float uv  = s2 * sc;
        out[b] = 1.0f / (1.0f + expf(-uv));
    }
}

// ---------------------------------------------------------------------------
extern "C" void kernel_launch(void* const* d_in, const int* in_sizes, int n_in,
                              void* d_out, int out_size, void* d_ws, size_t ws_size,
                              hipStream_t stream) {
    const int*   u          = (const int*)d_in[0];
    const int*   iidx       = (const int*)d_in[1];
    const int*   edges      = (const int*)d_in[2];
    const float* user_emb   = (const float*)d_in[3];
    const float* entity_emb = (const float*)d_in[4];
    const float* W1         = (const float*)d_in[5];
    const float* b1         = (const float*)d_in[6];
    const float* W2         = (const float*)d_in[7];
    const float* b2         = (const float*)d_in[8];
    float*       out        = (float*)d_out;

    char* ws = (char*)d_ws;
    int*            degi      = (int*)           (ws);
    float*          dinv      = (float*)         (ws + 100000u * 4);
    int*            row_start = (int*)           (ws + 200000u * 4);
    int*            gcursor   = (int*)           (ws + 300004u * 4);
    int*            partials  = (int*)           (ws + 300264u * 4);
    uint4*          w1p       = (uint4*)         (ws + 300656u * 4);
    uint4*          w2p       = (uint4*)         (ws + 304752u * 4);
    int*            srcs      = (int*)           (ws + 308848u * 4);
    unsigned short* emb_b     = (unsigned short*)(ws + 1908848u * 4);  // 2*(N+1)*32
    unsigned short* zb        = (unsigned short*)(ws + 3508864u * 4);  // 2*100032*32
    unsigned short* h2b       = (unsigned short*)(ws + 6711936u * 4);  // (N+1)*64
    unsigned int*   temp      = (unsigned int*)  (ws + 8311968u * 4);

    ginit_k<<<1, 256, 0, stream>>>(gcursor);
    packw_k<<<8, 256, 0, stream>>>(W1, W2, w1p, w2p);
    bin_k<<<NTILE, 256, 0, stream>>>(edges, gcursor, temp);
    count_k<<<NBUCK, 256, 0, stream>>>(temp, gcursor, degi);

    prep_k<<<N_ENT * 64 / 256 + 1, 256, 0, stream>>>(entity_emb, degi, dinv, emb_b);

    scan_partials<<<NBLK_SCAN, 256, 0, stream>>>(degi, partials);
    scan_offsets<<<1, 512, 0, stream>>>(partials, row_start);
    scan_apply<<<NBLK_SCAN, 256, 0, stream>>>(degi, partials, row_start);

    unbin_k<<<NBUCK, 256, 0, stream>>>(temp, gcursor, row_start, srcs);

    reduce1_k<<<2 * NBLK_R1, 256, 0, stream>>>(row_start, srcs, emb_b, dinv, zb);
    mlp_k<<<NBLK_G, 256, 0, stream>>>(zb, w1p, b1, w2p, dinv, h2b);

    reduce2f_k<<<BATCH * 64 / 256, 256, 0, stream>>>(u, iidx, user_emb, row_start,
                                                     srcs, h2b, dinv, b2, out);
}

// Round 2
// 244.777 us; speedup vs baseline: 1.0277x; 1.0277x over previous
//
#include <hip/hip_runtime.h>
#include <hip/hip_bf16.h>
#include <math.h>

// Problem constants (from reference)
constexpr int N_ENT = 100000;
constexpr int NEDGE = 1600000;
constexpr int BATCH = 8192;
constexpr int NBLK_SCAN = (N_ENT + 255) / 256;   // 391

// Bucketed CSR placement
constexpr int NBUCK   = 256;
constexpr int KNODE   = 391;                      // 256*391 >= N_ENT
constexpr int TILE    = 4096;
constexpr int NTILE   = (NEDGE + TILE - 1) / TILE; // 391
constexpr int BUCKCAP = 8192;                     // fixed bucket region

constexpr int NBLK_G = (N_ENT + 63) / 64;         // 1563 (64-row MLP tiles)
constexpr int ZROWS  = NBLK_G * 64;               // 100032 <= padded zb rows

// [R15 post-mortem] Planar 2x32-col split cut FETCH 156->116MB exactly as the
// L2-capacity model predicted, but dur REGRESSED 49.8->62.6us: the kernel is
// issue/latency-balanced, not miss-BW-bound. Reverted to interleaved 64-col
// rows; this round halves gather instruction count instead (uint4, 8
// lanes/row, 1KB per wave-load) at identical traffic.

// MFMA fragment types (gfx950; 8 bf16 = 4 VGPRs, 4 f32 acc)
typedef __attribute__((ext_vector_type(8))) short bf16x8;
typedef __attribute__((ext_vector_type(4))) float f32x4;

// bf16 helpers (RNE pack, exact unpack)
__device__ inline unsigned short f2b(float x) {
    unsigned int u = __float_as_uint(x);
    unsigned int r = (u + 0x7fffu + ((u >> 16) & 1u)) >> 16;
    return (unsigned short)r;
}
__device__ inline float b2f(unsigned short h) {
    return __uint_as_float(((unsigned int)h) << 16);
}
__device__ inline float blo(unsigned int p) { return __uint_as_float(p << 16); }
__device__ inline float bhi(unsigned int p) { return __uint_as_float(p & 0xffff0000u); }

// ---------------------------------------------------------------------------
// Workspace layout (4-byte units):
//  degi      : [0, 100000)
//  dinv      : [100000, 200000)
//  row_start : [200000, 300001)
//  gcursor   : [300004, 300260)
//  partials  : [300264, 300655)
//  w1p       : [300656, 304752)    uint4[1024] packed W1 B-frags (bf16)
//  w2p       : [304752, 308848)    uint4[1024] packed W2 B-frags (bf16)
//  srcs      : [308848, 1908848)
//  emb_b     : [1908848, 3508864)  ushort[(N+1)*64]
//  zb        : [3508864, 6711936)  ushort[100096*64] bf16 z (padded rows)
//  h2b       : [6711936, 8311968)  ushort[(N+1)*64]
//  temp      : [8311968, 10409120) uint[256*8192]
// Total ~41.6 MB.

// K1: prep — dinv + premultiplied bf16 entity rows (+ zero row at N_ENT)
__global__ __launch_bounds__(256) void prep_k(const float* __restrict__ emb,
                                              const int* __restrict__ degi,
                                              float* __restrict__ dinv,
                                              unsigned short* __restrict__ emb_b) {
    int gt   = blockIdx.x * 256 + threadIdx.x;
    int n    = gt >> 6;
    int lane = threadIdx.x & 63;
    if (n > N_ENT) return;
    if (n == N_ENT) { emb_b[(size_t)n * 64 + lane] = 0; return; }
    float v = emb[(size_t)n * 64 + lane];
    float s = v * v;
#pragma unroll
    for (int o = 32; o > 0; o >>= 1) s += __shfl_xor(s, o, 64);
    float nrm = sqrtf(s);
    float sc  = nrm > 1.0f ? 1.0f / nrm : 1.0f;
    float dv  = 1.0f / sqrtf((float)(degi[n] + 1));
    if (lane == 0) dinv[n] = dv;
    emb_b[(size_t)n * 64 + lane] = f2b(sc * dv * v);
}

// K0a: gcursor init to fixed bucket bases
__global__ __launch_bounds__(256) void ginit_k(int* __restrict__ gcursor) {
    gcursor[threadIdx.x] = threadIdx.x * BUCKCAP;
}

// K0p: pack W1/W2 into MFMA B-operand lane order (bf16).
// B-frag for mfma_f32_16x16x32_bf16: lane holds B[k = quad*8+j][n = lane&15].
// w1p entry e=(ct*2+s)*64+lane packs W1[s*32+quad*8+j][ct*16+li], j=0..7.
// w2p entry e=(ct*4+s)*64+lane packs W2[s*32+quad*8+j][ct*16+li].
__global__ __launch_bounds__(256) void packw_k(const float* __restrict__ W1g,
                                               const float* __restrict__ W2g,
                                               uint4* __restrict__ w1p,
                                               uint4* __restrict__ w2p) {
    int t = blockIdx.x * 256 + threadIdx.x;   // grid 8 -> 2048 threads
    int e    = t & 1023;
    int lane = e & 63, cs = e >> 6;
    int li   = lane & 15, quad = lane >> 4;
    unsigned short v[8];
    if (t < 1024) {
        int ct = cs >> 1, s = cs & 1;
        int kb = s * 32 + quad * 8;
        int n  = ct * 16 + li;
#pragma unroll
        for (int j = 0; j < 8; ++j) v[j] = f2b(W1g[(kb + j) * 128 + n]);
        uint4 p;
        p.x = (unsigned)v[0] | ((unsigned)v[1] << 16);
        p.y = (unsigned)v[2] | ((unsigned)v[3] << 16);
        p.z = (unsigned)v[4] | ((unsigned)v[5] << 16);
        p.w = (unsigned)v[6] | ((unsigned)v[7] << 16);
        w1p[e] = p;
    } else {
        int ct = cs >> 2, s = cs & 3;
        int kb = s * 32 + quad * 8;
        int n  = ct * 16 + li;
#pragma unroll
        for (int j = 0; j < 8; ++j) v[j] = f2b(W2g[(kb + j) * 64 + n]);
        uint4 p;
        p.x = (unsigned)v[0] | ((unsigned)v[1] << 16);
        p.y = (unsigned)v[2] | ((unsigned)v[3] << 16);
        p.z = (unsigned)v[4] | ((unsigned)v[5] << 16);
        p.w = (unsigned)v[6] | ((unsigned)v[7] << 16);
        w2p[e] = p;
    }
}

// K0b: bucket binning into fixed-capacity regions
__global__ __launch_bounds__(256) void bin_k(const int* __restrict__ edges,
                                             int* __restrict__ gcursor,
                                             unsigned int* __restrict__ temp) {
    __shared__ int cnt[NBUCK];
    __shared__ int gb[NBUCK];
    __shared__ int off[NBUCK];
    int tid  = threadIdx.x;
    int base = blockIdx.x * TILE;
    int sv[16], dv[16], bv[16];
    cnt[tid] = 0;
    __syncthreads();
#pragma unroll
    for (int i = 0; i < 16; ++i) {
        int e = base + i * 256 + tid;
        if (e < NEDGE) {
            sv[i] = edges[e];
            dv[i] = edges[NEDGE + e];
            bv[i] = dv[i] / KNODE;
            atomicAdd(&cnt[bv[i]], 1);
        } else {
            bv[i] = -1;
        }
    }
    __syncthreads();
    if (cnt[tid] > 0) gb[tid] = atomicAdd(&gcursor[tid], cnt[tid]);
    off[tid] = 0;
    __syncthreads();
#pragma unroll
    for (int i = 0; i < 16; ++i) {
        int b = bv[i];
        if (b >= 0) {
            int p  = atomicAdd(&off[b], 1);
            int dl = dv[i] - b * KNODE;
            temp[gb[b] + p] = ((unsigned int)sv[i] << 9) | (unsigned int)dl;
        }
    }
}

// K0c: per-bucket degree histogram from binned temp
__global__ __launch_bounds__(256) void count_k(const unsigned int* __restrict__ temp,
                                               const int* __restrict__ gcursor,
                                               int* __restrict__ degi) {
    __shared__ int cnt[KNODE];
    int b     = blockIdx.x;
    int node0 = b * KNODE;
    int nn    = N_ENT - node0; if (nn > KNODE) nn = KNODE;
    for (int i = threadIdx.x; i < KNODE; i += 256) cnt[i] = 0;
    __syncthreads();
    int tbeg = b * BUCKCAP;
    int tend = gcursor[b];
    for (int idx = tbeg + threadIdx.x; idx < tend; idx += 256)
        atomicAdd(&cnt[temp[idx] & 511u], 1);
    __syncthreads();
    for (int i = threadIdx.x; i < nn; i += 256) degi[node0 + i] = cnt[i];
}

// K3a/b/c: hierarchical exclusive scan of degi -> row_start
__global__ __launch_bounds__(256) void scan_partials(const int* __restrict__ degi,
                                                     int* __restrict__ partials) {
    __shared__ int ws[4];
    int i = blockIdx.x * 256 + threadIdx.x;
    int v = (i < N_ENT) ? degi[i] : 0;
#pragma unroll
    for (int o = 32; o > 0; o >>= 1) v += __shfl_xor(v, o, 64);
    if ((threadIdx.x & 63) == 0) ws[threadIdx.x >> 6] = v;
    __syncthreads();
    if (threadIdx.x == 0) partials[blockIdx.x] = ws[0] + ws[1] + ws[2] + ws[3];
}

__global__ __launch_bounds__(512) void scan_offsets(int* __restrict__ partials,
                                                    int* __restrict__ row_start) {
    __shared__ int ts[512];
    int t = threadIdx.x;
    int v = (t < NBLK_SCAN) ? partials[t] : 0;
    ts[t] = v;
    __syncthreads();
    for (int off = 1; off < 512; off <<= 1) {
        int x = (t >= off) ? ts[t - off] : 0;
        __syncthreads();
        ts[t] += x;
        __syncthreads();
    }
    if (t < NBLK_SCAN) partials[t] = ts[t] - v;
    if (t == 0) row_start[N_ENT] = NEDGE;
}

__global__ __launch_bounds__(256) void scan_apply(const int* __restrict__ degi,
                                                  const int* __restrict__ partials,
                                                  int* __restrict__ row_start) {
    __shared__ int ts[256];
    int t = threadIdx.x;
    int i = blockIdx.x * 256 + t;
    int v = (i < N_ENT) ? degi[i] : 0;
    ts[t] = v;
    __syncthreads();
    for (int off = 1; off < 256; off <<= 1) {
        int x = (t >= off) ? ts[t - off] : 0;
        __syncthreads();
        ts[t] += x;
        __syncthreads();
    }
    if (i < N_ENT) row_start[i] = ts[t] - v + partials[blockIdx.x];
}

// K4b: within-bucket placement
__global__ __launch_bounds__(256) void unbin_k(const unsigned int* __restrict__ temp,
                                               const int* __restrict__ gcursor,
                                               const int* __restrict__ row_start,
                                               int* __restrict__ srcs) {
    __shared__ int cur[KNODE];
    int b     = blockIdx.x;
    int node0 = b * KNODE;
    int nn    = N_ENT - node0; if (nn > KNODE) nn = KNODE;
    for (int i = threadIdx.x; i < nn; i += 256) cur[i] = row_start[node0 + i];
    __syncthreads();
    int tbeg = b * BUCKCAP;
    int tend = gcursor[b];
    for (int idx = tbeg + threadIdx.x; idx < tend; idx += 256) {
        unsigned int v = temp[idx];
        int dl = (int)(v & 511u);
        int s  = (int)(v >> 9);
        int pos = atomicAdd(&cur[dl], 1);
        srcs[pos] = s;
    }
}

// K5: layer-1 aggregate. uint4 gather: 8 lanes/row, 16B/lane, 1KB per
// wave-load. Per 64 edges: 8 loads + 8 shuffles (was 16+16 with uint2) at
// identical HBM traffic. Each lane accumulates 8 columns; 3x shfl_xor
// reduce over the sub axis; lanes 0..7 store one uint4 (128B row store).
__global__ __launch_bounds__(256) void reduce1_k(const int* __restrict__ row_start,
                                                 const int* __restrict__ srcs,
                                                 const unsigned short* __restrict__ emb_b,
                                                 const float* __restrict__ dinv,
                                                 unsigned short* __restrict__ zb) {
    int gt   = blockIdx.x * 256 + threadIdx.x;
    int dst  = gt >> 6;
    int lane = threadIdx.x & 63;
    int sub  = lane >> 3;      // 0..7: row slot within a 8-row load group
    int li   = lane & 7;       // 0..7: 16B segment within the 128B row
    int beg = row_start[dst];
    int end = row_start[dst + 1];
    float acc[8] = {0.f, 0.f, 0.f, 0.f, 0.f, 0.f, 0.f, 0.f};
    for (int base = beg; base < end; base += 64) {
        int cnt = end - base; if (cnt > 64) cnt = 64;
        int s_v = (base + lane < end) ? srcs[base + lane] : N_ENT;
        for (int jj = 0; jj < cnt; jj += 32) {
            int s0 = __shfl(s_v, jj + sub,      64);
            int s1 = __shfl(s_v, jj + 8 + sub,  64);
            int s2 = __shfl(s_v, jj + 16 + sub, 64);
            int s3 = __shfl(s_v, jj + 24 + sub, 64);
            uint4 p0 = *(const uint4*)(emb_b + (size_t)s0 * 64 + li * 8);
            uint4 p1 = *(const uint4*)(emb_b + (size_t)s1 * 64 + li * 8);
            uint4 p2 = *(const uint4*)(emb_b + (size_t)s2 * 64 + li * 8);
            uint4 p3 = *(const uint4*)(emb_b + (size_t)s3 * 64 + li * 8);
            acc[0] += blo(p0.x) + blo(p1.x) + blo(p2.x) + blo(p3.x);
            acc[1] += bhi(p0.x) + bhi(p1.x) + bhi(p2.x) + bhi(p3.x);
            acc[2] += blo(p0.y) + blo(p1.y) + blo(p2.y) + blo(p3.y);
            acc[3] += bhi(p0.y) + bhi(p1.y) + bhi(p2.y) + bhi(p3.y);
            acc[4] += blo(p0.z) + blo(p1.z) + blo(p2.z) + blo(p3.z);
            acc[5] += bhi(p0.z) + bhi(p1.z) + bhi(p2.z) + bhi(p3.z);
            acc[6] += blo(p0.w) + blo(p1.w) + blo(p2.w) + blo(p3.w);
            acc[7] += bhi(p0.w) + bhi(p1.w) + bhi(p2.w) + bhi(p3.w);
        }
    }
#pragma unroll
    for (int i = 0; i < 8; ++i) {
        acc[i] += __shfl_xor(acc[i], 8, 64);
        acc[i] += __shfl_xor(acc[i], 16, 64);
        acc[i] += __shfl_xor(acc[i], 32, 64);
    }
    if (lane < 8) {
        uint4 po = *(const uint4*)(emb_b + (size_t)dst * 64 + li * 8);
        float dv = dinv[dst];
        unsigned int h0 = f2b(dv * (acc[0] + blo(po.x)));
        unsigned int h1 = f2b(dv * (acc[1] + bhi(po.x)));
        unsigned int h2 = f2b(dv * (acc[2] + blo(po.y)));
        unsigned int h3 = f2b(dv * (acc[3] + bhi(po.y)));
        unsigned int h4 = f2b(dv * (acc[4] + blo(po.z)));
        unsigned int h5 = f2b(dv * (acc[5] + bhi(po.z)));
        unsigned int h6 = f2b(dv * (acc[6] + blo(po.w)));
        unsigned int h7 = f2b(dv * (acc[7] + bhi(po.w)));
        uint4 p;
        p.x = h0 | (h1 << 16);
        p.y = h2 | (h3 << 16);
        p.z = h4 | (h5 << 16);
        p.w = h6 | (h7 << 16);
        *(uint4*)(zb + (size_t)dst * 64 + li * 8) = p;
    }
}

// K6: fused MFMA MLP: h2b = bf16(dinv * (relu(zb@W1 + b1) @ W2)).
// One wave per 16-row strip, 4 strips per block. MFMA 16x16x32_bf16:
//   A-frag: lane holds A[m=lane&15][k=quad*8+j]     [m120-verified layout]
//   C/D   : lane holds D[row=quad*4+r][col=lane&15] [m89/m91]
// y1 (relu, bf16) round-trips through per-wave LDS between phases; h2b
// written via LDS transpose for coalesced uint4 stores.
__global__ __launch_bounds__(256) void mlp_k(const unsigned short* __restrict__ zb,
                                             const uint4* __restrict__ w1p,
                                             const float* __restrict__ b1,
                                             const uint4* __restrict__ w2p,
                                             const float* __restrict__ dinv,
                                             unsigned short* __restrict__ h2b) {
    __shared__ unsigned short y1s[4][16 * 136];   // per-wave y1 strip (pad 136)
    __shared__ unsigned short h2s[4][16 * 64];    // per-wave output strip
    int tid  = threadIdx.x;
    int w    = tid >> 6, lane = tid & 63;
    int li   = lane & 15, quad = lane >> 4;
    int r0   = blockIdx.x * 64 + w * 16;
    // phase-1 A frags (zb padded to 100096 rows; garbage rows masked at store)
    uint4 a0u = *(const uint4*)(zb + (size_t)(r0 + li) * 64 + quad * 8);
    uint4 a1u = *(const uint4*)(zb + (size_t)(r0 + li) * 64 + 32 + quad * 8);
    bf16x8 a0 = *(bf16x8*)&a0u;
    bf16x8 a1 = *(bf16x8*)&a1u;
    unsigned short* ys = y1s[w];
#pragma unroll
    for (int ct = 0; ct < 8; ++ct) {
        uint4 b0u = w1p[(ct * 2 + 0) * 64 + lane];
        uint4 b1u = w1p[(ct * 2 + 1) * 64 + lane];
        f32x4 acc = {0.f, 0.f, 0.f, 0.f};
        acc = __builtin_amdgcn_mfma_f32_16x16x32_bf16(a0, *(bf16x8*)&b0u, acc, 0, 0, 0);
        acc = __builtin_amdgcn_mfma_f32_16x16x32_bf16(a1, *(bf16x8*)&b1u, acc, 0, 0, 0);
        float bias = b1[ct * 16 + li];
#pragma unroll
        for (int r = 0; r < 4; ++r)
            ys[(quad * 4 + r) * 136 + ct * 16 + li] = f2b(fmaxf(acc[r] + bias, 0.f));
    }
    __syncthreads();
    // phase-2 A frags from LDS (A[m=li][k=s*32+quad*8+j])
    bf16x8 a2[4];
#pragma unroll
    for (int s = 0; s < 4; ++s) {
        uint4 au = *(const uint4*)(ys + li * 136 + s * 32 + quad * 8);
        a2[s] = *(bf16x8*)&au;
    }
    float dvr[4];
#pragma unroll
    for (int r = 0; r < 4; ++r) {
        int grow = r0 + quad * 4 + r;
        dvr[r] = (grow < N_ENT) ? dinv[grow] : 0.f;
    }
    unsigned short* hs = h2s[w];
#pragma unroll
    for (int ct = 0; ct < 4; ++ct) {
        f32x4 acc = {0.f, 0.f, 0.f, 0.f};
#pragma unroll
        for (int s = 0; s < 4; ++s) {
            uint4 bu = w2p[(ct * 4 + s) * 64 + lane];
            acc = __builtin_amdgcn_mfma_f32_16x16x32_bf16(a2[s], *(bf16x8*)&bu, acc, 0, 0, 0);
        }
#pragma unroll
        for (int r = 0; r < 4; ++r)
            hs[(quad * 4 + r) * 64 + ct * 16 + li] = f2b(acc[r] * dvr[r]);
    }
    __syncthreads();
    // coalesced store of the strip (2 uint4 per lane); zero row at N_ENT
#pragma unroll
    for (int q = 0; q < 2; ++q) {
        int t4   = lane * 2 + q;       // uint4 index within strip (0..127)
        int rl   = t4 >> 3;
        int c0   = (t4 & 7) * 8;
        int grow = r0 + rl;
        if (grow < N_ENT) {
            *(uint4*)(h2b + (size_t)grow * 64 + c0) = *(const uint4*)(hs + rl * 64 + c0);
        } else if (grow == N_ENT) {
            uint4 zz; zz.x = 0u; zz.y = 0u; zz.z = 0u; zz.w = 0u;
            *(uint4*)(h2b + (size_t)grow * 64 + c0) = zz;
        }
    }
}

// K8: fused layer-2 aggregate + final dot for the 8192 batch items.
// Same uint4 8-lanes/row gather as reduce1_k.
__global__ __launch_bounds__(256) void reduce2f_k(const int* __restrict__ u,
                                                  const int* __restrict__ iidx,
                                                  const float* __restrict__ uemb,
                                                  const int* __restrict__ row_start,
                                                  const int* __restrict__ srcs,
                                                  const unsigned short* __restrict__ h2b,
                                                  const float* __restrict__ dinv,
                                                  const float* __restrict__ b2,
                                                  float* __restrict__ out) {
    int gt   = blockIdx.x * 256 + threadIdx.x;
    int b    = gt >> 6;
    int lane = threadIdx.x & 63;
    int sub  = lane >> 3;
    int li   = lane & 7;
    int dst = iidx[b];
    int beg = row_start[dst];
    int end = row_start[dst + 1];
    float acc[8] = {0.f, 0.f, 0.f, 0.f, 0.f, 0.f, 0.f, 0.f};
    for (int base = beg; base < end; base += 64) {
        int cnt = end - base; if (cnt > 64) cnt = 64;
        int s_v = (base + lane < end) ? srcs[base + lane] : N_ENT;
        for (int jj = 0; jj < cnt; jj += 32) {
            int s0 = __shfl(s_v, jj + sub,      64);
            int s1 = __shfl(s_v, jj + 8 + sub,  64);
            int s2 = __shfl(s_v, jj + 16 + sub, 64);
            int s3 = __shfl(s_v, jj + 24 + sub, 64);
            uint4 p0 = *(const uint4*)(h2b + (size_t)s0 * 64 + li * 8);
            uint4 p1 = *(const uint4*)(h2b + (size_t)s1 * 64 + li * 8);
            uint4 p2 = *(const uint4*)(h2b + (size_t)s2 * 64 + li * 8);
            uint4 p3 = *(const uint4*)(h2b + (size_t)s3 * 64 + li * 8);
            acc[0] += blo(p0.x) + blo(p1.x) + blo(p2.x) + blo(p3.x);
            acc[1] += bhi(p0.x) + bhi(p1.x) + bhi(p2.x) + bhi(p3.x);
            acc[2] += blo(p0.y) + blo(p1.y) + blo(p2.y) + blo(p3.y);
            acc[3] += bhi(p0.y) + bhi(p1.y) + bhi(p2.y) + bhi(p3.y);
            acc[4] += blo(p0.z) + blo(p1.z) + blo(p2.z) + blo(p3.z);
            acc[5] += bhi(p0.z) + bhi(p1.z) + bhi(p2.z) + bhi(p3.z);
            acc[6] += blo(p0.w) + blo(p1.w) + blo(p2.w) + blo(p3.w);
            acc[7] += bhi(p0.w) + bhi(p1.w) + bhi(p2.w) + bhi(p3.w);
        }
    }
#pragma unroll
    for (int i = 0; i < 8; ++i) {
        acc[i] += __shfl_xor(acc[i], 8, 64);
        acc[i] += __shfl_xor(acc[i], 16, 64);
        acc[i] += __shfl_xor(acc[i], 32, 64);
    }
    float s1 = 0.f, s2 = 0.f;
    if (lane < 8) {
        uint4 po = *(const uint4*)(h2b + (size_t)dst * 64 + li * 8);
        float dv = dinv[dst];
        float4 bb0 = *(const float4*)(b2 + li * 8);
        float4 bb1 = *(const float4*)(b2 + li * 8 + 4);
        float z0 = dv * (acc[0] + blo(po.x)) + bb0.x;
        float z1 = dv * (acc[1] + bhi(po.x)) + bb0.y;
        float z2 = dv * (acc[2] + blo(po.y)) + bb0.z;
        float z3 = dv * (acc[3] + bhi(po.y)) + bb0.w;
        float z4 = dv * (acc[4] + blo(po.z)) + bb1.x;
        float z5 = dv * (acc[5] + bhi(po.z)) + bb1.y;
        float z6 = dv * (acc[6] + blo(po.w)) + bb1.z;
        float z7 = dv * (acc[7] + bhi(po.w)) + bb1.w;
        const float* ur = uemb + (size_t)u[b] * 64 + li * 8;
        float4 ue0 = *(const float4*)(ur);
        float4 ue1 = *(const float4*)(ur + 4);
        s1 = ue0.x * ue0.x + ue0.y * ue0.y + ue0.z * ue0.z + ue0.w * ue0.w
           + ue1.x * ue1.x + ue1.y * ue1.y + ue1.z * ue1.z + ue1.w * ue1.w;
        s2 = ue0.x * z0 + ue0.y * z1 + ue0.z * z2 + ue0.w * z3
           + ue1.x * z4 + ue1.y * z5 + ue1.z * z6 + ue1.w * z7;
    }
#pragma unroll
    for (int o = 4; o > 0; o >>= 1) {
        s1 += __shfl_xor(s1, o, 64);
        s2 += __shfl_xor(s2, o, 64);
    }
    if (lane == 0) {
        float nrm = sqrtf(s1);
        float sc  = nrm > 1.0f ? 1.0f / nrm : 1.0f;
        float uv  = s2 * sc;
        out[b] = 1.0f / (1.0f + expf(-uv));
    }
}

// ---------------------------------------------------------------------------
extern "C" void kernel_launch(void* const* d_in, const int* in_sizes, int n_in,
                              void* d_out, int out_size, void* d_ws, size_t ws_size,
                              hipStream_t stream) {
    const int*   u          = (const int*)d_in[0];
    const int*   iidx       = (const int*)d_in[1];
    const int*   edges      = (const int*)d_in[2];
    const float* user_emb   = (const float*)d_in[3];
    const float* entity_emb = (const float*)d_in[4];
    const float* W1         = (const float*)d_in[5];
    const float* b1         = (const float*)d_in[6];
    const float* W2         = (const float*)d_in[7];
    const float* b2         = (const float*)d_in[8];
    float*       out        = (float*)d_out;

    char* ws = (char*)d_ws;
    int*            degi      = (int*)           (ws);
    float*          dinv      = (float*)         (ws + 100000u * 4);
    int*            row_start = (int*)           (ws + 200000u * 4);
    int*            gcursor   = (int*)           (ws + 300004u * 4);
    int*            partials  = (int*)           (ws + 300264u * 4);
    uint4*          w1p       = (uint4*)         (ws + 300656u * 4);
    uint4*          w2p       = (uint4*)         (ws + 304752u * 4);
    int*            srcs      = (int*)           (ws + 308848u * 4);
    unsigned short* emb_b     = (unsigned short*)(ws + 1908848u * 4);  // (N+1)*64
    unsigned short* zb        = (unsigned short*)(ws + 3508864u * 4);  // 100096*64
    unsigned short* h2b       = (unsigned short*)(ws + 6711936u * 4);  // (N+1)*64
    unsigned int*   temp      = (unsigned int*)  (ws + 8311968u * 4);

    ginit_k<<<1, 256, 0, stream>>>(gcursor);
    packw_k<<<8, 256, 0, stream>>>(W1, W2, w1p, w2p);
    bin_k<<<NTILE, 256, 0, stream>>>(edges, gcursor, temp);
    count_k<<<NBUCK, 256, 0, stream>>>(temp, gcursor, degi);

    prep_k<<<N_ENT * 64 / 256 + 1, 256, 0, stream>>>(entity_emb, degi, dinv, emb_b);

    scan_partials<<<NBLK_SCAN, 256, 0, stream>>>(degi, partials);
    scan_offsets<<<1, 512, 0, stream>>>(partials, row_start);
    scan_apply<<<NBLK_SCAN, 256, 0, stream>>>(degi, partials, row_start);

    unbin_k<<<NBUCK, 256, 0, stream>>>(temp, gcursor, row_start, srcs);

    reduce1_k<<<N_ENT * 64 / 256, 256, 0, stream>>>(row_start, srcs, emb_b, dinv, zb);
    mlp_k<<<NBLK_G, 256, 0, stream>>>(zb, w1p, b1, w2p, dinv, h2b);

    reduce2f_k<<<BATCH * 64 / 256, 256, 0, stream>>>(u, iidx, user_emb, row_start,
                                                     srcs, h2b, dinv, b2, out);
}

// Round 3
// 238.154 us; speedup vs baseline: 1.0563x; 1.0278x over previous
//
#include <hip/hip_runtime.h>
#include <hip/hip_bf16.h>
#include <math.h>

// Problem constants (from reference)
constexpr int N_ENT = 100000;
constexpr int NEDGE = 1600000;
constexpr int BATCH = 8192;

// Bucketed CSR placement
constexpr int NBUCK   = 256;
constexpr int KNODE   = 391;                      // 256*391 >= N_ENT
constexpr int TILE    = 4096;
constexpr int NTILE   = (NEDGE + TILE - 1) / TILE; // 391
constexpr int BUCKCAP = 8192;                     // fixed bucket region

constexpr int NBLK_G = (N_ENT + 63) / 64;         // 1563 (64-row MLP tiles)
constexpr int ZROWS  = NBLK_G * 64;               // 100032 <= padded zb rows

// [R15/R16 post-mortem] reduce1_k is pinned at ~50us across 3 structurally
// different gathers (uint2/planar/uint4): random-128B-row gather floor
// (~3.4 TB/s beyond-L2). Reverted to the best (uint2, 49.8us). This round
// attacks the OTHER ~195us: bin_k's 48-VGPR staging (spill suspect) and
// launch count (12 -> 9: ginit+packw fused; scan_partials/scan_apply folded
// into scan_offsets-over-buckets + in-unbin 391-elem prefix scan).

// MFMA fragment types (gfx950; 8 bf16 = 4 VGPRs, 4 f32 acc)
typedef __attribute__((ext_vector_type(8))) short bf16x8;
typedef __attribute__((ext_vector_type(4))) float f32x4;

// bf16 helpers (RNE pack, exact unpack)
__device__ inline unsigned short f2b(float x) {
    unsigned int u = __float_as_uint(x);
    unsigned int r = (u + 0x7fffu + ((u >> 16) & 1u)) >> 16;
    return (unsigned short)r;
}
__device__ inline float blo(unsigned int p) { return __uint_as_float(p << 16); }
__device__ inline float bhi(unsigned int p) { return __uint_as_float(p & 0xffff0000u); }

// ---------------------------------------------------------------------------
// Workspace layout (4-byte units):
//  degi      : [0, 100000)
//  dinv      : [100000, 200000)
//  row_start : [200000, 300001)
//  gcursor   : [300004, 300260)
//  bucket_base:[300264, 300520)
//  w1p       : [300656, 304752)    uint4[1024] packed W1 B-frags (bf16)
//  w2p       : [304752, 308848)    uint4[1024] packed W2 B-frags (bf16)
//  srcs      : [308848, 1908848)
//  emb_b     : [1908848, 3508864)  ushort[(N+1)*64]
//  zb        : [3508864, 6711936)  ushort[100096*64] bf16 z (padded rows)
//  h2b       : [6711936, 8311968)  ushort[(N+1)*64]
//  temp      : [8311968, 10409120) uint[256*8192]
// Total ~41.6 MB.

// K1: prep — dinv + premultiplied bf16 entity rows (+ zero row at N_ENT)
__global__ __launch_bounds__(256) void prep_k(const float* __restrict__ emb,
                                              const int* __restrict__ degi,
                                              float* __restrict__ dinv,
                                              unsigned short* __restrict__ emb_b) {
    int gt   = blockIdx.x * 256 + threadIdx.x;
    int n    = gt >> 6;
    int lane = threadIdx.x & 63;
    if (n > N_ENT) return;
    if (n == N_ENT) { emb_b[(size_t)n * 64 + lane] = 0; return; }
    float v = emb[(size_t)n * 64 + lane];
    float s = v * v;
#pragma unroll
    for (int o = 32; o > 0; o >>= 1) s += __shfl_xor(s, o, 64);
    float nrm = sqrtf(s);
    float sc  = nrm > 1.0f ? 1.0f / nrm : 1.0f;
    float dv  = 1.0f / sqrtf((float)(degi[n] + 1));
    if (lane == 0) dinv[n] = dv;
    emb_b[(size_t)n * 64 + lane] = f2b(sc * dv * v);
}

// K0: fused gcursor-init + W1/W2 MFMA-layout pack (grid 9: block 8 = ginit).
// B-frag for mfma_f32_16x16x32_bf16: lane holds B[k = quad*8+j][n = lane&15].
__global__ __launch_bounds__(256) void init_k(const float* __restrict__ W1g,
                                              const float* __restrict__ W2g,
                                              uint4* __restrict__ w1p,
                                              uint4* __restrict__ w2p,
                                              int* __restrict__ gcursor) {
    if (blockIdx.x == 8) { gcursor[threadIdx.x] = threadIdx.x * BUCKCAP; return; }
    int t = blockIdx.x * 256 + threadIdx.x;   // 0..2047
    int e    = t & 1023;
    int lane = e & 63, cs = e >> 6;
    int li   = lane & 15, quad = lane >> 4;
    unsigned short v[8];
    if (t < 1024) {
        int ct = cs >> 1, s = cs & 1;
        int kb = s * 32 + quad * 8;
        int n  = ct * 16 + li;
#pragma unroll
        for (int j = 0; j < 8; ++j) v[j] = f2b(W1g[(kb + j) * 128 + n]);
        uint4 p;
        p.x = (unsigned)v[0] | ((unsigned)v[1] << 16);
        p.y = (unsigned)v[2] | ((unsigned)v[3] << 16);
        p.z = (unsigned)v[4] | ((unsigned)v[5] << 16);
        p.w = (unsigned)v[6] | ((unsigned)v[7] << 16);
        w1p[e] = p;
    } else {
        int ct = cs >> 2, s = cs & 3;
        int kb = s * 32 + quad * 8;
        int n  = ct * 16 + li;
#pragma unroll
        for (int j = 0; j < 8; ++j) v[j] = f2b(W2g[(kb + j) * 64 + n]);
        uint4 p;
        p.x = (unsigned)v[0] | ((unsigned)v[1] << 16);
        p.y = (unsigned)v[2] | ((unsigned)v[3] << 16);
        p.z = (unsigned)v[4] | ((unsigned)v[5] << 16);
        p.w = (unsigned)v[6] | ((unsigned)v[7] << 16);
        w2p[e] = p;
    }
}

// K0b: bucket binning. Staging packed to val[16] (src<<9|dl, 26 bits used)
// + bpk[4] (bucket id, 4x8b per uint): ~20 staging VGPRs vs the old 48
// (sv/dv/bv[16]) — spill-suspect fix. Single read of edges preserved.
__global__ __launch_bounds__(256) void bin_k(const int* __restrict__ edges,
                                             int* __restrict__ gcursor,
                                             unsigned int* __restrict__ temp) {
    __shared__ int cnt[NBUCK];
    __shared__ int gb[NBUCK];
    __shared__ int off[NBUCK];
    int tid  = threadIdx.x;
    int base = blockIdx.x * TILE;
    unsigned int val[16];
    unsigned int bpk[4] = {0u, 0u, 0u, 0u};
    cnt[tid] = 0;
    __syncthreads();
#pragma unroll
    for (int i = 0; i < 16; ++i) {
        int e = base + i * 256 + tid;
        unsigned int b = 0u;
        if (e < NEDGE) {
            int s  = edges[e];
            int d  = edges[NEDGE + e];
            int bb = d / KNODE;            // magic-mul
            int dl = d - bb * KNODE;
            val[i] = ((unsigned int)s << 9) | (unsigned int)dl;
            b = (unsigned int)bb;
            atomicAdd(&cnt[bb], 1);
        } else {
            val[i] = 0xffffffffu;          // invalid marker (valid < 2^26)
        }
        bpk[i >> 2] |= b << ((i & 3) * 8);
    }
    __syncthreads();
    if (cnt[tid] > 0) gb[tid] = atomicAdd(&gcursor[tid], cnt[tid]);
    off[tid] = 0;
    __syncthreads();
#pragma unroll
    for (int i = 0; i < 16; ++i) {
        if (val[i] != 0xffffffffu) {
            int b = (int)((bpk[i >> 2] >> ((i & 3) * 8)) & 255u);
            int p = atomicAdd(&off[b], 1);
            temp[gb[b] + p] = val[i];
        }
    }
}

// K0c: per-bucket degree histogram from binned temp
__global__ __launch_bounds__(256) void count_k(const unsigned int* __restrict__ temp,
                                               const int* __restrict__ gcursor,
                                               int* __restrict__ degi) {
    __shared__ int cnt[KNODE];
    int b     = blockIdx.x;
    int node0 = b * KNODE;
    int nn    = N_ENT - node0; if (nn > KNODE) nn = KNODE;
    for (int i = threadIdx.x; i < KNODE; i += 256) cnt[i] = 0;
    __syncthreads();
    int tbeg = b * BUCKCAP;
    int tend = gcursor[b];
    for (int idx = tbeg + threadIdx.x; idx < tend; idx += 256)
        atomicAdd(&cnt[temp[idx] & 511u], 1);
    __syncthreads();
    for (int i = threadIdx.x; i < nn; i += 256) degi[node0 + i] = cnt[i];
}

// K3: bucket-level exclusive scan. Bucket totals are gcursor[b]-b*BUCKCAP
// directly — no per-node partials pass needed.
__global__ __launch_bounds__(256) void scan_offsets(const int* __restrict__ gcursor,
                                                    int* __restrict__ bucket_base,
                                                    int* __restrict__ row_start) {
    __shared__ int ts[NBUCK];
    int t = threadIdx.x;
    int v = gcursor[t] - t * BUCKCAP;
    ts[t] = v;
    __syncthreads();
    for (int off = 1; off < NBUCK; off <<= 1) {
        int x = (t >= off) ? ts[t - off] : 0;
        __syncthreads();
        ts[t] += x;
        __syncthreads();
    }
    bucket_base[t] = ts[t] - v;
    if (t == 0) row_start[N_ENT] = NEDGE;
}

// K4: within-bucket placement + row_start production. Wave 0 does the
// 391-element prefix scan of degi (7 elems/lane, wave-scan of lane sums),
// writes row_start and seeds cur[]; then all 256 threads place edges.
__global__ __launch_bounds__(256) void unbin_k(const unsigned int* __restrict__ temp,
                                               const int* __restrict__ gcursor,
                                               const int* __restrict__ bucket_base,
                                               const int* __restrict__ degi,
                                               int* __restrict__ row_start,
                                               int* __restrict__ srcs) {
    __shared__ int cur[KNODE];
    int b     = blockIdx.x;
    int node0 = b * KNODE;
    int nn    = N_ENT - node0; if (nn > KNODE) nn = KNODE;
    int tid   = threadIdx.x;
    if (tid < 64) {
        int lane = tid;
        int loc[7];
        int s = 0;
#pragma unroll
        for (int j = 0; j < 7; ++j) {
            int idx = lane * 7 + j;
            int d = (idx < nn) ? degi[node0 + idx] : 0;
            loc[j] = s;
            s += d;
        }
        // exclusive wave-scan of per-lane sums
        int v = s;
#pragma unroll
        for (int o = 1; o < 64; o <<= 1) {
            int x = __shfl_up(v, o, 64);
            if (lane >= o) v += x;
        }
        int pfx  = v - s;
        int base = bucket_base[b];
#pragma unroll
        for (int j = 0; j < 7; ++j) {
            int idx = lane * 7 + j;
            if (idx < nn) {
                int rs = base + pfx + loc[j];
                cur[idx] = rs;
                row_start[node0 + idx] = rs;
            }
        }
    }
    __syncthreads();
    int tbeg = b * BUCKCAP;
    int tend = gcursor[b];
    for (int idx = tbeg + tid; idx < tend; idx += 256) {
        unsigned int v = temp[idx];
        int dl = (int)(v & 511u);
        int s  = (int)(v >> 9);
        int pos = atomicAdd(&cur[dl], 1);
        srcs[pos] = s;
    }
}

// K5: layer-1 aggregate, 4 edges per gather instruction (uint2, 16 lanes/row
// — best measured variant, 49.8us); bf16 output rows.
__global__ __launch_bounds__(256) void reduce1_k(const int* __restrict__ row_start,
                                                 const int* __restrict__ srcs,
                                                 const unsigned short* __restrict__ emb_b,
                                                 const float* __restrict__ dinv,
                                                 unsigned short* __restrict__ zb) {
    int gt   = blockIdx.x * 256 + threadIdx.x;
    int dst  = gt >> 6;
    int lane = threadIdx.x & 63;
    int sub  = lane >> 4;
    int li   = lane & 15;
    int beg = row_start[dst];
    int end = row_start[dst + 1];
    float4 acc = make_float4(0.f, 0.f, 0.f, 0.f);
    for (int base = beg; base < end; base += 64) {
        int cnt = end - base; if (cnt > 64) cnt = 64;
        int s_v = (base + lane < end) ? srcs[base + lane] : N_ENT;
        for (int jj = 0; jj < cnt; jj += 16) {
            int s0 = __shfl(s_v, jj + sub,      64);
            int s1 = __shfl(s_v, jj + 4 + sub,  64);
            int s2 = __shfl(s_v, jj + 8 + sub,  64);
            int s3 = __shfl(s_v, jj + 12 + sub, 64);
            uint2 p0 = *(const uint2*)(emb_b + (size_t)s0 * 64 + li * 4);
            uint2 p1 = *(const uint2*)(emb_b + (size_t)s1 * 64 + li * 4);
            uint2 p2 = *(const uint2*)(emb_b + (size_t)s2 * 64 + li * 4);
            uint2 p3 = *(const uint2*)(emb_b + (size_t)s3 * 64 + li * 4);
            acc.x += blo(p0.x) + blo(p1.x) + blo(p2.x) + blo(p3.x);
            acc.y += bhi(p0.x) + bhi(p1.x) + bhi(p2.x) + bhi(p3.x);
            acc.z += blo(p0.y) + blo(p1.y) + blo(p2.y) + blo(p3.y);
            acc.w += bhi(p0.y) + bhi(p1.y) + bhi(p2.y) + bhi(p3.y);
        }
    }
    acc.x += __shfl_xor(acc.x, 16, 64); acc.y += __shfl_xor(acc.y, 16, 64);
    acc.z += __shfl_xor(acc.z, 16, 64); acc.w += __shfl_xor(acc.w, 16, 64);
    acc.x += __shfl_xor(acc.x, 32, 64); acc.y += __shfl_xor(acc.y, 32, 64);
    acc.z += __shfl_xor(acc.z, 32, 64); acc.w += __shfl_xor(acc.w, 32, 64);
    if (lane < 16) {
        uint2 po = *(const uint2*)(emb_b + (size_t)dst * 64 + li * 4);
        float dv = dinv[dst];
        unsigned int h0 = f2b(dv * (acc.x + blo(po.x)));
        unsigned int h1 = f2b(dv * (acc.y + bhi(po.x)));
        unsigned int h2 = f2b(dv * (acc.z + blo(po.y)));
        unsigned int h3 = f2b(dv * (acc.w + bhi(po.y)));
        uint2 p;
        p.x = h0 | (h1 << 16);
        p.y = h2 | (h3 << 16);
        *(uint2*)(zb + (size_t)dst * 64 + li * 4) = p;
    }
}

// K6: fused MFMA MLP: h2b = bf16(dinv * (relu(zb@W1 + b1) @ W2)).
// One wave per 16-row strip, 4 strips per block. MFMA 16x16x32_bf16:
//   A-frag: lane holds A[m=lane&15][k=quad*8+j]     [m120-verified layout]
//   C/D   : lane holds D[row=quad*4+r][col=lane&15] [m89/m91]
__global__ __launch_bounds__(256) void mlp_k(const unsigned short* __restrict__ zb,
                                             const uint4* __restrict__ w1p,
                                             const float* __restrict__ b1,
                                             const uint4* __restrict__ w2p,
                                             const float* __restrict__ dinv,
                                             unsigned short* __restrict__ h2b) {
    __shared__ unsigned short y1s[4][16 * 136];   // per-wave y1 strip (pad 136)
    __shared__ unsigned short h2s[4][16 * 64];    // per-wave output strip
    int tid  = threadIdx.x;
    int w    = tid >> 6, lane = tid & 63;
    int li   = lane & 15, quad = lane >> 4;
    int r0   = blockIdx.x * 64 + w * 16;
    uint4 a0u = *(const uint4*)(zb + (size_t)(r0 + li) * 64 + quad * 8);
    uint4 a1u = *(const uint4*)(zb + (size_t)(r0 + li) * 64 + 32 + quad * 8);
    bf16x8 a0 = *(bf16x8*)&a0u;
    bf16x8 a1 = *(bf16x8*)&a1u;
    unsigned short* ys = y1s[w];
#pragma unroll
    for (int ct = 0; ct < 8; ++ct) {
        uint4 b0u = w1p[(ct * 2 + 0) * 64 + lane];
        uint4 b1u = w1p[(ct * 2 + 1) * 64 + lane];
        f32x4 acc = {0.f, 0.f, 0.f, 0.f};
        acc = __builtin_amdgcn_mfma_f32_16x16x32_bf16(a0, *(bf16x8*)&b0u, acc, 0, 0, 0);
        acc = __builtin_amdgcn_mfma_f32_16x16x32_bf16(a1, *(bf16x8*)&b1u, acc, 0, 0, 0);
        float bias = b1[ct * 16 + li];
#pragma unroll
        for (int r = 0; r < 4; ++r)
            ys[(quad * 4 + r) * 136 + ct * 16 + li] = f2b(fmaxf(acc[r] + bias, 0.f));
    }
    __syncthreads();
    bf16x8 a2[4];
#pragma unroll
    for (int s = 0; s < 4; ++s) {
        uint4 au = *(const uint4*)(ys + li * 136 + s * 32 + quad * 8);
        a2[s] = *(bf16x8*)&au;
    }
    float dvr[4];
#pragma unroll
    for (int r = 0; r < 4; ++r) {
        int grow = r0 + quad * 4 + r;
        dvr[r] = (grow < N_ENT) ? dinv[grow] : 0.f;
    }
    unsigned short* hs = h2s[w];
#pragma unroll
    for (int ct = 0; ct < 4; ++ct) {
        f32x4 acc = {0.f, 0.f, 0.f, 0.f};
#pragma unroll
        for (int s = 0; s < 4; ++s) {
            uint4 bu = w2p[(ct * 4 + s) * 64 + lane];
            acc = __builtin_amdgcn_mfma_f32_16x16x32_bf16(a2[s], *(bf16x8*)&bu, acc, 0, 0, 0);
        }
#pragma unroll
        for (int r = 0; r < 4; ++r)
            hs[(quad * 4 + r) * 64 + ct * 16 + li] = f2b(acc[r] * dvr[r]);
    }
    __syncthreads();
#pragma unroll
    for (int q = 0; q < 2; ++q) {
        int t4   = lane * 2 + q;
        int rl   = t4 >> 3;
        int c0   = (t4 & 7) * 8;
        int grow = r0 + rl;
        if (grow < N_ENT) {
            *(uint4*)(h2b + (size_t)grow * 64 + c0) = *(const uint4*)(hs + rl * 64 + c0);
        } else if (grow == N_ENT) {
            uint4 zz; zz.x = 0u; zz.y = 0u; zz.z = 0u; zz.w = 0u;
            *(uint4*)(h2b + (size_t)grow * 64 + c0) = zz;
        }
    }
}

// K8: fused layer-2 aggregate + final dot for the 8192 batch items.
__global__ __launch_bounds__(256) void reduce2f_k(const int* __restrict__ u,
                                                  const int* __restrict__ iidx,
                                                  const float* __restrict__ uemb,
                                                  const int* __restrict__ row_start,
                                                  const int* __restrict__ srcs,
                                                  const unsigned short* __restrict__ h2b,
                                                  const float* __restrict__ dinv,
                                                  const float* __restrict__ b2,
                                                  float* __restrict__ out) {
    int gt   = blockIdx.x * 256 + threadIdx.x;
    int b    = gt >> 6;
    int lane = threadIdx.x & 63;
    int sub  = lane >> 4;
    int li   = lane & 15;
    int dst = iidx[b];
    int beg = row_start[dst];
    int end = row_start[dst + 1];
    float4 acc = make_float4(0.f, 0.f, 0.f, 0.f);
    for (int base = beg; base < end; base += 64) {
        int cnt = end - base; if (cnt > 64) cnt = 64;
        int s_v = (base + lane < end) ? srcs[base + lane] : N_ENT;
        for (int jj = 0; jj < cnt; jj += 16) {
            int s0 = __shfl(s_v, jj + sub,      64);
            int s1 = __shfl(s_v, jj + 4 + sub,  64);
            int s2 = __shfl(s_v, jj + 8 + sub,  64);
            int s3 = __shfl(s_v, jj + 12 + sub, 64);
            uint2 p0 = *(const uint2*)(h2b + (size_t)s0 * 64 + li * 4);
            uint2 p1 = *(const uint2*)(h2b + (size_t)s1 * 64 + li * 4);
            uint2 p2 = *(const uint2*)(h2b + (size_t)s2 * 64 + li * 4);
            uint2 p3 = *(const uint2*)(h2b + (size_t)s3 * 64 + li * 4);
            acc.x += blo(p0.x) + blo(p1.x) + blo(p2.x) + blo(p3.x);
            acc.y += bhi(p0.x) + bhi(p1.x) + bhi(p2.x) + bhi(p3.x);
            acc.z += blo(p0.y) + blo(p1.y) + blo(p2.y) + blo(p3.y);
            acc.w += bhi(p0.y) + bhi(p1.y) + bhi(p2.y) + bhi(p3.y);
        }
    }
    acc.x += __shfl_xor(acc.x, 16, 64); acc.y += __shfl_xor(acc.y, 16, 64);
    acc.z += __shfl_xor(acc.z, 16, 64); acc.w += __shfl_xor(acc.w, 16, 64);
    acc.x += __shfl_xor(acc.x, 32, 64); acc.y += __shfl_xor(acc.y, 32, 64);
    acc.z += __shfl_xor(acc.z, 32, 64); acc.w += __shfl_xor(acc.w, 32, 64);
    float s1 = 0.f, s2 = 0.f;
    if (lane < 16) {
        uint2 po = *(const uint2*)(h2b + (size_t)dst * 64 + li * 4);
        float dv = dinv[dst];
        float4 bb = *(const float4*)(b2 + li * 4);
        float4 z2v;
        z2v.x = dv * (acc.x + blo(po.x)) + bb.x;
        z2v.y = dv * (acc.y + bhi(po.x)) + bb.y;
        z2v.z = dv * (acc.z + blo(po.y)) + bb.z;
        z2v.w = dv * (acc.w + bhi(po.y)) + bb.w;
        float4 ue = *(const float4*)(uemb + (size_t)u[b] * 64 + li * 4);
        s1 = ue.x * ue.x + ue.y * ue.y + ue.z * ue.z + ue.w * ue.w;
        s2 = ue.x * z2v.x + ue.y * z2v.y + ue.z * z2v.z + ue.w * z2v.w;
    }
#pragma unroll
    for (int o = 8; o > 0; o >>= 1) {
        s1 += __shfl_xor(s1, o, 64);
        s2 += __shfl_xor(s2, o, 64);
    }
    if (lane == 0) {
        float nrm = sqrtf(s1);
        float sc  = nrm > 1.0f ? 1.0f / nrm : 1.0f;
        float uv  = s2 * sc;
        out[b] = 1.0f / (1.0f + expf(-uv));
    }
}

// ---------------------------------------------------------------------------
extern "C" void kernel_launch(void* const* d_in, const int* in_sizes, int n_in,
                              void* d_out, int out_size, void* d_ws, size_t ws_size,
                              hipStream_t stream) {
    const int*   u          = (const int*)d_in[0];
    const int*   iidx       = (const int*)d_in[1];
    const int*   edges      = (const int*)d_in[2];
    const float* user_emb   = (const float*)d_in[3];
    const float* entity_emb = (const float*)d_in[4];
    const float* W1         = (const float*)d_in[5];
    const float* b1         = (const float*)d_in[6];
    const float* W2         = (const float*)d_in[7];
    const float* b2         = (const float*)d_in[8];
    float*       out        = (float*)d_out;

    char* ws = (char*)d_ws;
    int*            degi        = (int*)           (ws);
    float*          dinv        = (float*)         (ws + 100000u * 4);
    int*            row_start   = (int*)           (ws + 200000u * 4);
    int*            gcursor     = (int*)           (ws + 300004u * 4);
    int*            bucket_base = (int*)           (ws + 300264u * 4);
    uint4*          w1p         = (uint4*)         (ws + 300656u * 4);
    uint4*          w2p         = (uint4*)         (ws + 304752u * 4);
    int*            srcs        = (int*)           (ws + 308848u * 4);
    unsigned short* emb_b       = (unsigned short*)(ws + 1908848u * 4);  // (N+1)*64
    unsigned short* zb          = (unsigned short*)(ws + 3508864u * 4);  // 100096*64
    unsigned short* h2b         = (unsigned short*)(ws + 6711936u * 4);  // (N+1)*64
    unsigned int*   temp        = (unsigned int*)  (ws + 8311968u * 4);

    init_k<<<9, 256, 0, stream>>>(W1, W2, w1p, w2p, gcursor);
    bin_k<<<NTILE, 256, 0, stream>>>(edges, gcursor, temp);
    count_k<<<NBUCK, 256, 0, stream>>>(temp, gcursor, degi);
    scan_offsets<<<1, 256, 0, stream>>>(gcursor, bucket_base, row_start);

    prep_k<<<N_ENT * 64 / 256 + 1, 256, 0, stream>>>(entity_emb, degi, dinv, emb_b);

    unbin_k<<<NBUCK, 256, 0, stream>>>(temp, gcursor, bucket_base, degi,
                                       row_start, srcs);

    reduce1_k<<<N_ENT * 64 / 256, 256, 0, stream>>>(row_start, srcs, emb_b, dinv, zb);
    mlp_k<<<NBLK_G, 256, 0, stream>>>(zb, w1p, b1, w2p, dinv, h2b);

    reduce2f_k<<<BATCH * 64 / 256, 256, 0, stream>>>(u, iidx, user_emb, row_start,
                                                     srcs, h2b, dinv, b2, out);
}

// Round 4
// 234.169 us; speedup vs baseline: 1.0742x; 1.0170x over previous
//
#include <hip/hip_runtime.h>
#include <hip/hip_bf16.h>
#include <math.h>

// Problem constants (from reference)
constexpr int N_ENT = 100000;
constexpr int NEDGE = 1600000;
constexpr int BATCH = 8192;

// Bucketed CSR placement
constexpr int NBUCK   = 256;
constexpr int KNODE   = 391;                      // 256*391 >= N_ENT
constexpr int TILE    = 4096;
constexpr int NTILE   = (NEDGE + TILE - 1) / TILE; // 391
constexpr int BUCKCAP = 8192;                     // fixed bucket region

constexpr int NBLK_G = (N_ENT + 63) / 64;         // 1563 (64-row MLP tiles)
constexpr int ZROWS  = NBLK_G * 64;               // 100032 <= padded zb rows

// [R17 journal] reduce1 ~50us == beyond-L2 random-line floor (156MB @
// ~3.1TB/s); 3 gather variants all pinned. This round: (a) split reduce1
// into 2 half-dispatches so top-5 profiling exposes the hidden ~188us tier;
// (b) fuse count+scan+unbin into unbinC (temp staged in LDS, read once;
// degi eliminated -- prep derives degree from row_start diff; packw rides
// in 8 spare blocks). 9 -> 8 dispatches, -20MB intermediate traffic.

// MFMA fragment types (gfx950; 8 bf16 = 4 VGPRs, 4 f32 acc)
typedef __attribute__((ext_vector_type(8))) short bf16x8;
typedef __attribute__((ext_vector_type(4))) float f32x4;

// bf16 helpers (RNE pack, exact unpack)
__device__ inline unsigned short f2b(float x) {
    unsigned int u = __float_as_uint(x);
    unsigned int r = (u + 0x7fffu + ((u >> 16) & 1u)) >> 16;
    return (unsigned short)r;
}
__device__ inline float blo(unsigned int p) { return __uint_as_float(p << 16); }
__device__ inline float bhi(unsigned int p) { return __uint_as_float(p & 0xffff0000u); }

// ---------------------------------------------------------------------------
// Workspace layout (4-byte units; identical footprint to R16, 41.6 MB):
//  (degi slot unused)    [0, 100000)
//  dinv      : [100000, 200000)
//  row_start : [200000, 300001)
//  gcursor   : [300004, 300260)
//  w1p       : [300656, 304752)    uint4[1024] packed W1 B-frags (bf16)
//  w2p       : [304752, 308848)    uint4[1024] packed W2 B-frags (bf16)
//  srcs      : [308848, 1908848)
//  emb_b     : [1908848, 3508864)  ushort[(N+1)*64]
//  zb        : [3508864, 6711936)  ushort[100096*64] bf16 z (padded rows)
//  h2b       : [6711936, 8311968)  ushort[(N+1)*64]
//  temp      : [8311968, 10409120) uint[256*8192]

// K0: gcursor init to fixed bucket bases
__global__ __launch_bounds__(256) void ginit_k(int* __restrict__ gcursor) {
    gcursor[threadIdx.x] = threadIdx.x * BUCKCAP;
}

// K1: bucket binning (packed staging: val = src<<9|dl, bucket ids 4x8b)
__global__ __launch_bounds__(256) void bin_k(const int* __restrict__ edges,
                                             int* __restrict__ gcursor,
                                             unsigned int* __restrict__ temp) {
    __shared__ int cnt[NBUCK];
    __shared__ int gb[NBUCK];
    __shared__ int off[NBUCK];
    int tid  = threadIdx.x;
    int base = blockIdx.x * TILE;
    unsigned int val[16];
    unsigned int bpk[4] = {0u, 0u, 0u, 0u};
    cnt[tid] = 0;
    __syncthreads();
#pragma unroll
    for (int i = 0; i < 16; ++i) {
        int e = base + i * 256 + tid;
        unsigned int b = 0u;
        if (e < NEDGE) {
            int s  = edges[e];
            int d  = edges[NEDGE + e];
            int bb = d / KNODE;            // magic-mul
            int dl = d - bb * KNODE;
            val[i] = ((unsigned int)s << 9) | (unsigned int)dl;
            b = (unsigned int)bb;
            atomicAdd(&cnt[bb], 1);
        } else {
            val[i] = 0xffffffffu;          // invalid marker (valid < 2^26)
        }
        bpk[i >> 2] |= b << ((i & 3) * 8);
    }
    __syncthreads();
    if (cnt[tid] > 0) gb[tid] = atomicAdd(&gcursor[tid], cnt[tid]);
    off[tid] = 0;
    __syncthreads();
#pragma unroll
    for (int i = 0; i < 16; ++i) {
        if (val[i] != 0xffffffffu) {
            int b = (int)((bpk[i >> 2] >> ((i & 3) * 8)) & 255u);
            int p = atomicAdd(&off[b], 1);
            temp[gb[b] + p] = val[i];
        }
    }
}

// K2: fused count + scan + placement (+ packw in blocks 256..263).
// Blocks 0..255: stage bucket's temp in LDS (read once), histogram,
// in-block scan of gcursor deltas -> bucket_base, wave-scan of 391 node
// degrees -> row_start + cur, then place srcs from LDS.
__global__ __launch_bounds__(256) void unbinC_k(const unsigned int* __restrict__ temp,
                                                const int* __restrict__ gcursor,
                                                const float* __restrict__ W1g,
                                                const float* __restrict__ W2g,
                                                uint4* __restrict__ w1p,
                                                uint4* __restrict__ w2p,
                                                int* __restrict__ row_start,
                                                int* __restrict__ srcs) {
    __shared__ unsigned int st[BUCKCAP];   // 32 KB bucket stage
    __shared__ int bs[NBUCK];
    __shared__ int cnt[KNODE];
    __shared__ int cur[KNODE];
    int b   = blockIdx.x;
    int tid = threadIdx.x;
    if (b >= NBUCK) {
        // weight pack: 8 blocks -> 2048 threads
        int t    = (b - NBUCK) * 256 + tid;
        int e    = t & 1023;
        int lane = e & 63, cs = e >> 6;
        int li   = lane & 15, quad = lane >> 4;
        unsigned short v[8];
        if (t < 1024) {
            int ct = cs >> 1, s = cs & 1;
            int kb = s * 32 + quad * 8;
            int n  = ct * 16 + li;
#pragma unroll
            for (int j = 0; j < 8; ++j) v[j] = f2b(W1g[(kb + j) * 128 + n]);
            uint4 p;
            p.x = (unsigned)v[0] | ((unsigned)v[1] << 16);
            p.y = (unsigned)v[2] | ((unsigned)v[3] << 16);
            p.z = (unsigned)v[4] | ((unsigned)v[5] << 16);
            p.w = (unsigned)v[6] | ((unsigned)v[7] << 16);
            w1p[e] = p;
        } else {
            int ct = cs >> 2, s = cs & 3;
            int kb = s * 32 + quad * 8;
            int n  = ct * 16 + li;
#pragma unroll
            for (int j = 0; j < 8; ++j) v[j] = f2b(W2g[(kb + j) * 64 + n]);
            uint4 p;
            p.x = (unsigned)v[0] | ((unsigned)v[1] << 16);
            p.y = (unsigned)v[2] | ((unsigned)v[3] << 16);
            p.z = (unsigned)v[4] | ((unsigned)v[5] << 16);
            p.w = (unsigned)v[6] | ((unsigned)v[7] << 16);
            w2p[e] = p;
        }
        return;
    }
    // bucket_base: in-block exclusive scan of per-bucket counts
    int myc = gcursor[tid] - tid * BUCKCAP;
    bs[tid] = myc;
    __syncthreads();
    for (int off = 1; off < NBUCK; off <<= 1) {
        int x = (tid >= off) ? bs[tid - off] : 0;
        __syncthreads();
        bs[tid] += x;
        __syncthreads();
    }
    int node0 = b * KNODE;
    int nn    = N_ENT - node0; if (nn > KNODE) nn = KNODE;
    int tbeg  = b * BUCKCAP;
    int m     = gcursor[b] - tbeg;
    int bucket_base = bs[b] - m;
    for (int i = tid; i < KNODE; i += 256) cnt[i] = 0;
    __syncthreads();
    // stage + histogram (single global read of temp)
    for (int i = tid; i < m; i += 256) {
        unsigned int x = temp[tbeg + i];
        st[i] = x;
        atomicAdd(&cnt[x & 511u], 1);
    }
    if (b == 0 && tid == 255) row_start[N_ENT] = NEDGE;
    __syncthreads();
    // wave 0: 391-element prefix scan (7/lane) -> cur + row_start
    if (tid < 64) {
        int lane = tid;
        int loc[7];
        int s = 0;
#pragma unroll
        for (int j = 0; j < 7; ++j) {
            int idx = lane * 7 + j;
            int d = (idx < nn) ? cnt[idx] : 0;
            loc[j] = s;
            s += d;
        }
        int v = s;
#pragma unroll
        for (int o = 1; o < 64; o <<= 1) {
            int x = __shfl_up(v, o, 64);
            if (lane >= o) v += x;
        }
        int pfx = v - s;
#pragma unroll
        for (int j = 0; j < 7; ++j) {
            int idx = lane * 7 + j;
            if (idx < nn) {
                int rs = bucket_base + pfx + loc[j];
                cur[idx] = rs;
                row_start[node0 + idx] = rs;
            }
        }
    }
    __syncthreads();
    // placement from LDS
    for (int i = tid; i < m; i += 256) {
        unsigned int x = st[i];
        int dl  = (int)(x & 511u);
        int pos = atomicAdd(&cur[dl], 1);
        srcs[pos] = (int)(x >> 9);
    }
}

// K3: prep — dinv (from row_start diff) + premultiplied bf16 entity rows
// (+ zero row at N_ENT)
__global__ __launch_bounds__(256) void prep_k(const float* __restrict__ emb,
                                              const int* __restrict__ row_start,
                                              float* __restrict__ dinv,
                                              unsigned short* __restrict__ emb_b) {
    int gt   = blockIdx.x * 256 + threadIdx.x;
    int n    = gt >> 6;
    int lane = threadIdx.x & 63;
    if (n > N_ENT) return;
    if (n == N_ENT) { emb_b[(size_t)n * 64 + lane] = 0; return; }
    float v = emb[(size_t)n * 64 + lane];
    float s = v * v;
#pragma unroll
    for (int o = 32; o > 0; o >>= 1) s += __shfl_xor(s, o, 64);
    float nrm = sqrtf(s);
    float sc  = nrm > 1.0f ? 1.0f / nrm : 1.0f;
    int   deg = row_start[n + 1] - row_start[n];
    float dv  = 1.0f / sqrtf((float)(deg + 1));
    if (lane == 0) dinv[n] = dv;
    emb_b[(size_t)n * 64 + lane] = f2b(sc * dv * v);
}

// K4: layer-1 aggregate (uint2, 16 lanes/row — best measured). Launched as
// two half-grid dispatches (dst0 = 0 and 50000) for profiling visibility.
__global__ __launch_bounds__(256) void reduce1_k(int dst0,
                                                 const int* __restrict__ row_start,
                                                 const int* __restrict__ srcs,
                                                 const unsigned short* __restrict__ emb_b,
                                                 const float* __restrict__ dinv,
                                                 unsigned short* __restrict__ zb) {
    int gt   = blockIdx.x * 256 + threadIdx.x;
    int dst  = dst0 + (gt >> 6);
    int lane = threadIdx.x & 63;
    int sub  = lane >> 4;
    int li   = lane & 15;
    int beg = row_start[dst];
    int end = row_start[dst + 1];
    float4 acc = make_float4(0.f, 0.f, 0.f, 0.f);
    for (int base = beg; base < end; base += 64) {
        int cnt = end - base; if (cnt > 64) cnt = 64;
        int s_v = (base + lane < end) ? srcs[base + lane] : N_ENT;
        for (int jj = 0; jj < cnt; jj += 16) {
            int s0 = __shfl(s_v, jj + sub,      64);
            int s1 = __shfl(s_v, jj + 4 + sub,  64);
            int s2 = __shfl(s_v, jj + 8 + sub,  64);
            int s3 = __shfl(s_v, jj + 12 + sub, 64);
            uint2 p0 = *(const uint2*)(emb_b + (size_t)s0 * 64 + li * 4);
            uint2 p1 = *(const uint2*)(emb_b + (size_t)s1 * 64 + li * 4);
            uint2 p2 = *(const uint2*)(emb_b + (size_t)s2 * 64 + li * 4);
            uint2 p3 = *(const uint2*)(emb_b + (size_t)s3 * 64 + li * 4);
            acc.x += blo(p0.x) + blo(p1.x) + blo(p2.x) + blo(p3.x);
            acc.y += bhi(p0.x) + bhi(p1.x) + bhi(p2.x) + bhi(p3.x);
            acc.z += blo(p0.y) + blo(p1.y) + blo(p2.y) + blo(p3.y);
            acc.w += bhi(p0.y) + bhi(p1.y) + bhi(p2.y) + bhi(p3.y);
        }
    }
    acc.x += __shfl_xor(acc.x, 16, 64); acc.y += __shfl_xor(acc.y, 16, 64);
    acc.z += __shfl_xor(acc.z, 16, 64); acc.w += __shfl_xor(acc.w, 16, 64);
    acc.x += __shfl_xor(acc.x, 32, 64); acc.y += __shfl_xor(acc.y, 32, 64);
    acc.z += __shfl_xor(acc.z, 32, 64); acc.w += __shfl_xor(acc.w, 32, 64);
    if (lane < 16) {
        uint2 po = *(const uint2*)(emb_b + (size_t)dst * 64 + li * 4);
        float dv = dinv[dst];
        unsigned int h0 = f2b(dv * (acc.x + blo(po.x)));
        unsigned int h1 = f2b(dv * (acc.y + bhi(po.x)));
        unsigned int h2 = f2b(dv * (acc.z + blo(po.y)));
        unsigned int h3 = f2b(dv * (acc.w + bhi(po.y)));
        uint2 p;
        p.x = h0 | (h1 << 16);
        p.y = h2 | (h3 << 16);
        *(uint2*)(zb + (size_t)dst * 64 + li * 4) = p;
    }
}

// K5: fused MFMA MLP: h2b = bf16(dinv * (relu(zb@W1 + b1) @ W2)).
__global__ __launch_bounds__(256) void mlp_k(const unsigned short* __restrict__ zb,
                                             const uint4* __restrict__ w1p,
                                             const float* __restrict__ b1,
                                             const uint4* __restrict__ w2p,
                                             const float* __restrict__ dinv,
                                             unsigned short* __restrict__ h2b) {
    __shared__ unsigned short y1s[4][16 * 136];   // per-wave y1 strip (pad 136)
    __shared__ unsigned short h2s[4][16 * 64];    // per-wave output strip
    int tid  = threadIdx.x;
    int w    = tid >> 6, lane = tid & 63;
    int li   = lane & 15, quad = lane >> 4;
    int r0   = blockIdx.x * 64 + w * 16;
    uint4 a0u = *(const uint4*)(zb + (size_t)(r0 + li) * 64 + quad * 8);
    uint4 a1u = *(const uint4*)(zb + (size_t)(r0 + li) * 64 + 32 + quad * 8);
    bf16x8 a0 = *(bf16x8*)&a0u;
    bf16x8 a1 = *(bf16x8*)&a1u;
    unsigned short* ys = y1s[w];
#pragma unroll
    for (int ct = 0; ct < 8; ++ct) {
        uint4 b0u = w1p[(ct * 2 + 0) * 64 + lane];
        uint4 b1u = w1p[(ct * 2 + 1) * 64 + lane];
        f32x4 acc = {0.f, 0.f, 0.f, 0.f};
        acc = __builtin_amdgcn_mfma_f32_16x16x32_bf16(a0, *(bf16x8*)&b0u, acc, 0, 0, 0);
        acc = __builtin_amdgcn_mfma_f32_16x16x32_bf16(a1, *(bf16x8*)&b1u, acc, 0, 0, 0);
        float bias = b1[ct * 16 + li];
#pragma unroll
        for (int r = 0; r < 4; ++r)
            ys[(quad * 4 + r) * 136 + ct * 16 + li] = f2b(fmaxf(acc[r] + bias, 0.f));
    }
    __syncthreads();
    bf16x8 a2[4];
#pragma unroll
    for (int s = 0; s < 4; ++s) {
        uint4 au = *(const uint4*)(ys + li * 136 + s * 32 + quad * 8);
        a2[s] = *(bf16x8*)&au;
    }
    float dvr[4];
#pragma unroll
    for (int r = 0; r < 4; ++r) {
        int grow = r0 + quad * 4 + r;
        dvr[r] = (grow < N_ENT) ? dinv[grow] : 0.f;
    }
    unsigned short* hs = h2s[w];
#pragma unroll
    for (int ct = 0; ct < 4; ++ct) {
        f32x4 acc = {0.f, 0.f, 0.f, 0.f};
#pragma unroll
        for (int s = 0; s < 4; ++s) {
            uint4 bu = w2p[(ct * 4 + s) * 64 + lane];
            acc = __builtin_amdgcn_mfma_f32_16x16x32_bf16(a2[s], *(bf16x8*)&bu, acc, 0, 0, 0);
        }
#pragma unroll
        for (int r = 0; r < 4; ++r)
            hs[(quad * 4 + r) * 64 + ct * 16 + li] = f2b(acc[r] * dvr[r]);
    }
    __syncthreads();
#pragma unroll
    for (int q = 0; q < 2; ++q) {
        int t4   = lane * 2 + q;
        int rl   = t4 >> 3;
        int c0   = (t4 & 7) * 8;
        int grow = r0 + rl;
        if (grow < N_ENT) {
            *(uint4*)(h2b + (size_t)grow * 64 + c0) = *(const uint4*)(hs + rl * 64 + c0);
        } else if (grow == N_ENT) {
            uint4 zz; zz.x = 0u; zz.y = 0u; zz.z = 0u; zz.w = 0u;
            *(uint4*)(h2b + (size_t)grow * 64 + c0) = zz;
        }
    }
}

// K6: fused layer-2 aggregate + final dot for the 8192 batch items.
__global__ __launch_bounds__(256) void reduce2f_k(const int* __restrict__ u,
                                                  const int* __restrict__ iidx,
                                                  const float* __restrict__ uemb,
                                                  const int* __restrict__ row_start,
                                                  const int* __restrict__ srcs,
                                                  const unsigned short* __restrict__ h2b,
                                                  const float* __restrict__ dinv,
                                                  const float* __restrict__ b2,
                                                  float* __restrict__ out) {
    int gt   = blockIdx.x * 256 + threadIdx.x;
    int b    = gt >> 6;
    int lane = threadIdx.x & 63;
    int sub  = lane >> 4;
    int li   = lane & 15;
    int dst = iidx[b];
    int beg = row_start[dst];
    int end = row_start[dst + 1];
    float4 acc = make_float4(0.f, 0.f, 0.f, 0.f);
    for (int base = beg; base < end; base += 64) {
        int cnt = end - base; if (cnt > 64) cnt = 64;
        int s_v = (base + lane < end) ? srcs[base + lane] : N_ENT;
        for (int jj = 0; jj < cnt; jj += 16) {
            int s0 = __shfl(s_v, jj + sub,      64);
            int s1 = __shfl(s_v, jj + 4 + sub,  64);
            int s2 = __shfl(s_v, jj + 8 + sub,  64);
            int s3 = __shfl(s_v, jj + 12 + sub, 64);
            uint2 p0 = *(const uint2*)(h2b + (size_t)s0 * 64 + li * 4);
            uint2 p1 = *(const uint2*)(h2b + (size_t)s1 * 64 + li * 4);
            uint2 p2 = *(const uint2*)(h2b + (size_t)s2 * 64 + li * 4);
            uint2 p3 = *(const uint2*)(h2b + (size_t)s3 * 64 + li * 4);
            acc.x += blo(p0.x) + blo(p1.x) + blo(p2.x) + blo(p3.x);
            acc.y += bhi(p0.x) + bhi(p1.x) + bhi(p2.x) + bhi(p3.x);
            acc.z += blo(p0.y) + blo(p1.y) + blo(p2.y) + blo(p3.y);
            acc.w += bhi(p0.y) + bhi(p1.y) + bhi(p2.y) + bhi(p3.y);
        }
    }
    acc.x += __shfl_xor(acc.x, 16, 64); acc.y += __shfl_xor(acc.y, 16, 64);
    acc.z += __shfl_xor(acc.z, 16, 64); acc.w += __shfl_xor(acc.w, 16, 64);
    acc.x += __shfl_xor(acc.x, 32, 64); acc.y += __shfl_xor(acc.y, 32, 64);
    acc.z += __shfl_xor(acc.z, 32, 64); acc.w += __shfl_xor(acc.w, 32, 64);
    float s1 = 0.f, s2 = 0.f;
    if (lane < 16) {
        uint2 po = *(const uint2*)(h2b + (size_t)dst * 64 + li * 4);
        float dv = dinv[dst];
        float4 bb = *(const float4*)(b2 + li * 4);
        float4 z2v;
        z2v.x = dv * (acc.x + blo(po.x)) + bb.x;
        z2v.y = dv * (acc.y + bhi(po.x)) + bb.y;
        z2v.z = dv * (acc.z + blo(po.y)) + bb.z;
        z2v.w = dv * (acc.w + bhi(po.y)) + bb.w;
        float4 ue = *(const float4*)(uemb + (size_t)u[b] * 64 + li * 4);
        s1 = ue.x * ue.x + ue.y * ue.y + ue.z * ue.z + ue.w * ue.w;
        s2 = ue.x * z2v.x + ue.y * z2v.y + ue.z * z2v.z + ue.w * z2v.w;
    }
#pragma unroll
    for (int o = 8; o > 0; o >>= 1) {
        s1 += __shfl_xor(s1, o, 64);
        s2 += __shfl_xor(s2, o, 64);
    }
    if (lane == 0) {
        float nrm = sqrtf(s1);
        float sc  = nrm > 1.0f ? 1.0f / nrm : 1.0f;
        float uv  = s2 * sc;
        out[b] = 1.0f / (1.0f + expf(-uv));
    }
}

// ---------------------------------------------------------------------------
extern "C" void kernel_launch(void* const* d_in, const int* in_sizes, int n_in,
                              void* d_out, int out_size, void* d_ws, size_t ws_size,
                              hipStream_t stream) {
    const int*   u          = (const int*)d_in[0];
    const int*   iidx       = (const int*)d_in[1];
    const int*   edges      = (const int*)d_in[2];
    const float* user_emb   = (const float*)d_in[3];
    const float* entity_emb = (const float*)d_in[4];
    const float* W1         = (const float*)d_in[5];
    const float* b1         = (const float*)d_in[6];
    const float* W2         = (const float*)d_in[7];
    const float* b2         = (const float*)d_in[8];
    float*       out        = (float*)d_out;

    char* ws = (char*)d_ws;
    float*          dinv      = (float*)         (ws + 100000u * 4);
    int*            row_start = (int*)           (ws + 200000u * 4);
    int*            gcursor   = (int*)           (ws + 300004u * 4);
    uint4*          w1p       = (uint4*)         (ws + 300656u * 4);
    uint4*          w2p       = (uint4*)         (ws + 304752u * 4);
    int*            srcs      = (int*)           (ws + 308848u * 4);
    unsigned short* emb_b     = (unsigned short*)(ws + 1908848u * 4);  // (N+1)*64
    unsigned short* zb        = (unsigned short*)(ws + 3508864u * 4);  // 100096*64
    unsigned short* h2b       = (unsigned short*)(ws + 6711936u * 4);  // (N+1)*64
    unsigned int*   temp      = (unsigned int*)  (ws + 8311968u * 4);

    ginit_k<<<1, 256, 0, stream>>>(gcursor);
    bin_k<<<NTILE, 256, 0, stream>>>(edges, gcursor, temp);
    unbinC_k<<<NBUCK + 8, 256, 0, stream>>>(temp, gcursor, W1, W2, w1p, w2p,
                                            row_start, srcs);
    prep_k<<<N_ENT * 64 / 256 + 1, 256, 0, stream>>>(entity_emb, row_start,
                                                     dinv, emb_b);

    reduce1_k<<<12500, 256, 0, stream>>>(0,     row_start, srcs, emb_b, dinv, zb);
    reduce1_k<<<12500, 256, 0, stream>>>(50000, row_start, srcs, emb_b, dinv, zb);
    mlp_k<<<NBLK_G, 256, 0, stream>>>(zb, w1p, b1, w2p, dinv, h2b);

    reduce2f_k<<<BATCH * 64 / 256, 256, 0, stream>>>(u, iidx, user_emb, row_start,
                                                     srcs, h2b, dinv, b2, out);
}